// Round 11
// baseline (929.429 us; speedup 1.0000x reference)
//
#include <hip/hip_runtime.h>

#define B_ 256
#define T_ 128
#define M_ (B_ * T_)
#define DH_ 256

__device__ __forceinline__ float sigf(float x) { return 1.0f / (1.0f + __expf(-x)); }
__device__ __forceinline__ float dot4(float4 a, float4 b) {
  return a.x * b.x + a.y * b.y + a.z * b.z + a.w * b.w;
}

typedef _Float16 half2v __attribute__((ext_vector_type(2)));
typedef short short8 __attribute__((ext_vector_type(8)));
typedef float f32x4 __attribute__((ext_vector_type(4)));

__device__ __forceinline__ float fdot2f(unsigned int w, unsigned int h, float acc) {
  half2v wv = __builtin_bit_cast(half2v, w);
  half2v hv = __builtin_bit_cast(half2v, h);
#if __has_builtin(__builtin_amdgcn_fdot2)
  return __builtin_amdgcn_fdot2(wv, hv, acc, false);
#else
  return acc + (float)wv[0] * (float)hv[0] + (float)wv[1] * (float)hv[1];
#endif
}
__device__ __forceinline__ unsigned int pk16(float a, float b) {
  unsigned short lo = __builtin_bit_cast(unsigned short, (_Float16)a);
  unsigned short hi = __builtin_bit_cast(unsigned short, (_Float16)b);
  return (unsigned int)lo | ((unsigned int)hi << 16);
}
__device__ __forceinline__ unsigned short bf16c(float x) {  // RNE f32->bf16
  unsigned int u = __builtin_bit_cast(unsigned int, x);
  return (unsigned short)((u + 0x7FFFu + ((u >> 16) & 1u)) >> 16);
}
__device__ __forceinline__ unsigned int bfpk(float a, float b) {
  return (unsigned int)bf16c(a) | ((unsigned int)bf16c(b) << 16);
}

// ---------------------------------------------------------------------------
// prep: combined biases; bf16 zero-padded GEMM weights (input projections,
// dialogue projection, per-modality FC); fp16-packed recurrent weights
// (dialogue reg/LDS split + modality register rows).
// ---------------------------------------------------------------------------
__global__ void prep_kernel(const float* __restrict__ w_ih_d, const float* __restrict__ w_hh_d,
                            const float* __restrict__ b_ih_d, const float* __restrict__ b_hh_d,
                            const float* __restrict__ b_ih0, const float* __restrict__ b_hh0,
                            const float* __restrict__ b_ih1, const float* __restrict__ b_hh1,
                            const float* __restrict__ b_ih2, const float* __restrict__ b_hh2,
                            const float* __restrict__ w_hh0, const float* __restrict__ w_hh1,
                            const float* __restrict__ w_hh2,
                            const float* __restrict__ w_ih0, const float* __restrict__ w_ih1,
                            const float* __restrict__ w_ih2,
                            const float* __restrict__ fc_w0, const float* __restrict__ fc_w1,
                            const float* __restrict__ fc_w2,
                            unsigned short* __restrict__ dfeat_h,
                            float* __restrict__ biasd, float* __restrict__ bias0,
                            float* __restrict__ bias1, float* __restrict__ bias2,
                            unsigned int* __restrict__ wpk, unsigned int* __restrict__ wldsg,
                            unsigned int* __restrict__ wpk0, unsigned int* __restrict__ wpk1,
                            unsigned int* __restrict__ wpk2,
                            unsigned short* __restrict__ w0b, unsigned short* __restrict__ w1b,
                            unsigned short* __restrict__ w2b, unsigned short* __restrict__ wdb,
                            unsigned short* __restrict__ fcw0b, unsigned short* __restrict__ fcw1b,
                            unsigned short* __restrict__ fcw2b) {
  int idx = blockIdx.x * blockDim.x + threadIdx.x;
  int stride = gridDim.x * blockDim.x;
  // bf16 GEMM weights (K zero-padded to multiple of 32)
  for (int i = idx; i < 512 * 320; i += stride) {
    int r = i / 320, k = i % 320;
    w0b[i] = (k < 300) ? bf16c(w_ih0[(size_t)r * 300 + k]) : (unsigned short)0;
  }
  for (int i = idx; i < 256 * 128; i += stride) {
    int r = i >> 7, k = i & 127;
    w1b[i] = (k < 100) ? bf16c(w_ih1[(size_t)r * 100 + k]) : (unsigned short)0;
  }
  for (int i = idx; i < 512 * 512; i += stride) w2b[i] = bf16c(w_ih2[i]);
  for (int i = idx; i < 1024 * 256; i += stride) {
    int r = i >> 8, k = i & 255;
    wdb[i] = (k < 250) ? bf16c(w_ih_d[(size_t)r * 250 + k]) : (unsigned short)0;
  }
  // FC weights bf16, rows zero-padded to 128/64
  for (int i = idx; i < 128 * 128; i += stride) {
    int f = i >> 7, k = i & 127;
    fcw0b[i] = (f < 100) ? bf16c(fc_w0[(size_t)f * 128 + k]) : (unsigned short)0;
    fcw2b[i] = (f < 100) ? bf16c(fc_w2[(size_t)f * 128 + k]) : (unsigned short)0;
  }
  for (int i = idx; i < 64 * 64; i += stride) {
    int f = i >> 6, k = i & 63;
    fcw1b[i] = (f < 50) ? bf16c(fc_w1[(size_t)f * 64 + k]) : (unsigned short)0;
  }
  for (int i = idx; i < M_ * 6; i += stride)   // zero dfeat_h pad cols 250..255
    dfeat_h[(size_t)(i / 6) * 256 + 250 + (i % 6)] = 0;
  // dialogue recurrent weights fp16: reg part (pairs 0..95), row r = gate row
  for (int i = idx; i < 1024 * 96; i += stride) {
    int r = i / 96, k0 = (i % 96) * 2;
    wpk[i] = pk16(w_hh_d[(size_t)r * 256 + k0], w_hh_d[(size_t)r * 256 + k0 + 1]);
  }
  // dialogue LDS part, b128 layout: i = (jj*1024 + r)*4 + q, pair p = 96+4*jj+q
  for (int i = idx; i < 32768; i += stride) {
    int jj = i >> 12, rem = i & 4095, r = rem >> 2, q = rem & 3;
    int p = 96 + 4 * jj + q;
    wldsg[i] = pk16(w_hh_d[(size_t)r * 256 + 2 * p], w_hh_d[(size_t)r * 256 + 2 * p + 1]);
  }
  // modality recurrent weights (row-major packed pairs)
  for (int i = idx; i < 512 * 64; i += stride) {
    int r = i >> 6, p = (i & 63) * 2;
    wpk0[i] = pk16(w_hh0[(size_t)r * 128 + p], w_hh0[(size_t)r * 128 + p + 1]);
    wpk2[i] = pk16(w_hh2[(size_t)r * 128 + p], w_hh2[(size_t)r * 128 + p + 1]);
  }
  for (int i = idx; i < 256 * 32; i += stride) {
    int r = i >> 5, p = (i & 31) * 2;
    wpk1[i] = pk16(w_hh1[(size_t)r * 64 + p], w_hh1[(size_t)r * 64 + p + 1]);
  }
  for (int i = idx; i < 1024; i += stride) biasd[i] = b_ih_d[i] + b_hh_d[i];
  for (int i = idx; i < 512; i += stride) bias0[i] = b_ih0[i] + b_hh0[i];
  for (int i = idx; i < 256; i += stride) bias1[i] = b_ih1[i] + b_hh1[i];
  for (int i = idx; i < 512; i += stride) bias2[i] = b_ih2[i] + b_hh2[i];
}

// ---------------------------------------------------------------------------
// mfma_gemm: C[m][n] = scale * sum_k X[m][k]*W[n][k] + bias[n], bf16 MFMA.
// (unchanged — verified)
// ---------------------------------------------------------------------------
template <bool XF16>
__global__ __launch_bounds__(256) void mfma_gemm(
    const void* __restrict__ Xv, const unsigned short* __restrict__ Wb,
    const float* __restrict__ bias, const float* __restrict__ umask,
    float* __restrict__ C, int K, int Kp, int N) {
  __shared__ __align__(16) unsigned short Xs[64][40];
  __shared__ __align__(16) unsigned short Ws[64][40];
  const int tid = threadIdx.x;
  const int d = blockIdx.x;
  const int nx = N >> 6;
  const int n0 = ((d % (nx << 3)) >> 3) << 6;
  const int m0 = (((d / (nx << 3)) << 3) + (d & 7)) << 6;
  const int srow = tid >> 2, kq = tid & 3;
  const int w = tid >> 6, lane = tid & 63;
  const int lr = lane & 15, lk = lane >> 4;
  const float* Xf = nullptr;
  const unsigned short* Xh = nullptr;
  if constexpr (XF16) {
    Xh = (const unsigned short*)Xv + (size_t)(m0 + srow) * Kp;
  } else {
    const int t = m0 >> 8, b0 = m0 & 255;
    Xf = (const float*)Xv + ((size_t)(b0 + srow) * T_ + t) * K;
  }
  const unsigned short* Wr = Wb + (size_t)(n0 + srow) * Kp;
  f32x4 acc[4];
#pragma unroll
  for (int j = 0; j < 4; j++) acc[j] = (f32x4){0.f, 0.f, 0.f, 0.f};

  for (int k0 = 0; k0 < Kp; k0 += 32) {
    uint4 xa;
    const int kk = k0 + kq * 8;
    if constexpr (XF16) {
      xa = *reinterpret_cast<const uint4*>(Xh + kk);
    } else {
      float4 va = (kk + 3 < K) ? *reinterpret_cast<const float4*>(Xf + kk)
                               : make_float4(0.f, 0.f, 0.f, 0.f);
      float4 vb = (kk + 7 < K) ? *reinterpret_cast<const float4*>(Xf + kk + 4)
                               : make_float4(0.f, 0.f, 0.f, 0.f);
      xa.x = bfpk(va.x, va.y); xa.y = bfpk(va.z, va.w);
      xa.z = bfpk(vb.x, vb.y); xa.w = bfpk(vb.z, vb.w);
    }
    uint4 wv = *reinterpret_cast<const uint4*>(Wr + kk);
    __syncthreads();
    *reinterpret_cast<uint4*>(&Xs[srow][kq * 8]) = xa;
    *reinterpret_cast<uint4*>(&Ws[srow][kq * 8]) = wv;
    __syncthreads();
    short8 af = *reinterpret_cast<const short8*>(&Xs[w * 16 + lr][lk * 8]);
#pragma unroll
    for (int j = 0; j < 4; j++) {
      short8 bf = *reinterpret_cast<const short8*>(&Ws[j * 16 + lr][lk * 8]);
      acc[j] = __builtin_amdgcn_mfma_f32_16x16x32_bf16(af, bf, acc[j], 0, 0, 0);
    }
  }
#pragma unroll
  for (int j = 0; j < 4; j++) {
    const int col = n0 + j * 16 + lr;
    const float bv = bias[col];
#pragma unroll
    for (int r = 0; r < 4; r++) {
      const int mrow = m0 + w * 16 + lk * 4 + r;
      float um = 1.0f;
      if constexpr (!XF16)
        um = umask[((m0 & 255) + w * 16 + lk * 4 + r) * T_ + (m0 >> 8)];
      C[(size_t)mrow * N + col] = acc[j][r] * um + bv;
    }
  }
}

// ---------------------------------------------------------------------------
// fc_gemm: per-modality FC head as bf16 MFMA GEMM (out of the scan).
// ---------------------------------------------------------------------------
__global__ __launch_bounds__(256) void fc_gemm(
    const unsigned short* __restrict__ Xh, const unsigned short* __restrict__ Wb,
    const float* __restrict__ fcb, const float* __restrict__ umask,
    unsigned short* __restrict__ dfeat_h, int Kp, int nx, int F, int col0) {
  __shared__ __align__(16) unsigned short Xs[64][40];
  __shared__ __align__(16) unsigned short Ws[64][40];
  const int tid = threadIdx.x;
  const int n0 = (blockIdx.x % nx) * 64;
  const int m0 = (blockIdx.x / nx) * 64;
  const int srow = tid >> 2, kq = tid & 3;
  const int w = tid >> 6, lane = tid & 63;
  const int lr = lane & 15, lk = lane >> 4;
  const unsigned short* Xp = Xh + (size_t)(m0 + srow) * Kp;
  const unsigned short* Wr = Wb + (size_t)(n0 + srow) * Kp;
  f32x4 acc[4];
#pragma unroll
  for (int j = 0; j < 4; j++) acc[j] = (f32x4){0.f, 0.f, 0.f, 0.f};
  for (int k0 = 0; k0 < Kp; k0 += 32) {
    const int kk = k0 + kq * 8;
    uint4 xa = *reinterpret_cast<const uint4*>(Xp + kk);
    uint4 wv = *reinterpret_cast<const uint4*>(Wr + kk);
    __syncthreads();
    *reinterpret_cast<uint4*>(&Xs[srow][kq * 8]) = xa;
    *reinterpret_cast<uint4*>(&Ws[srow][kq * 8]) = wv;
    __syncthreads();
    short8 af = *reinterpret_cast<const short8*>(&Xs[w * 16 + lr][lk * 8]);
#pragma unroll
    for (int j = 0; j < 4; j++) {
      short8 bf = *reinterpret_cast<const short8*>(&Ws[j * 16 + lr][lk * 8]);
      acc[j] = __builtin_amdgcn_mfma_f32_16x16x32_bf16(af, bf, acc[j], 0, 0, 0);
    }
  }
#pragma unroll
  for (int j = 0; j < 4; j++) {
    const int coln = n0 + j * 16 + lr;
    const float bv = (coln < F) ? fcb[coln] : 0.f;
#pragma unroll
    for (int r = 0; r < 4; r++) {
      const int mrow = m0 + w * 16 + lk * 4 + r;
      if (coln < F) {
        const int t = mrow >> 8, b = mrow & 255;
        float um = umask[b * T_ + t];
        dfeat_h[(size_t)mrow * 256 + col0 + coln] = bf16c(tanhf(acc[j][r] + bv) * um);
      }
    }
  }
}

// ---------------------------------------------------------------------------
// mod_scan: fused modality LSTM scans (FC evicted; h -> hallm bf16).
// EXACT round-8 configuration (measured good): waves_per_eu(2,3), no pins.
// ---------------------------------------------------------------------------
struct ModScanArgs {
  const float* gx0; const float* gx1; const float* gx2;
  const unsigned int* wk0; const unsigned int* wk1; const unsigned int* wk2;
  unsigned short* hm0; unsigned short* hm1; unsigned short* hm2;
};

__device__ __forceinline__ void mod_body128s(
    const float* __restrict__ gx, const unsigned int* __restrict__ wk,
    int b, unsigned short* __restrict__ hallm, unsigned int* smem) {
  float* gbuf = (float*)smem;          // 512 f32
  unsigned int* hbuf = smem + 512;     // 64 u32
  const int tid = threadIdx.x;
  uint4 wrA[16], wrB[16];
  {
    const uint4* wpA = reinterpret_cast<const uint4*>(wk + (size_t)tid * 64);
    const uint4* wpB = reinterpret_cast<const uint4*>(wk + (size_t)(tid + 256) * 64);
#pragma unroll
    for (int j = 0; j < 16; j++) { wrA[j] = wpA[j]; wrB[j] = wpB[j]; }
  }
  if (tid < 64) hbuf[tid] = 0u;
  float creg = 0.f;
  __syncthreads();
  const uint4* h4 = reinterpret_cast<const uint4*>(hbuf);
  const float* gp = gx + (size_t)b * 512 + tid;
  float gcA = gp[0], gcB = gp[256];
  for (int t = 0; t < T_; t++) {
    float gnA = 0.f, gnB = 0.f;
    if (t + 1 < T_) {
      gnA = gp[(size_t)(t + 1) * B_ * 512];
      gnB = gp[(size_t)(t + 1) * B_ * 512 + 256];
    }
    float a0 = 0.f, a1 = 0.f, a2 = 0.f, a3 = 0.f;
    float d0 = 0.f, d1 = 0.f, d2 = 0.f, d3 = 0.f;
#pragma unroll
    for (int j = 0; j < 16; j++) {
      uint4 hv = h4[j];
      a0 = fdot2f(wrA[j].x, hv.x, a0);
      a1 = fdot2f(wrA[j].y, hv.y, a1);
      a2 = fdot2f(wrA[j].z, hv.z, a2);
      a3 = fdot2f(wrA[j].w, hv.w, a3);
      d0 = fdot2f(wrB[j].x, hv.x, d0);
      d1 = fdot2f(wrB[j].y, hv.y, d1);
      d2 = fdot2f(wrB[j].z, hv.z, d2);
      d3 = fdot2f(wrB[j].w, hv.w, d3);
    }
    gbuf[tid] = (a0 + a1) + (a2 + a3) + gcA;      // gx includes bias + umask'd x
    gbuf[tid + 256] = (d0 + d1) + (d2 + d3) + gcB;
    gcA = gnA; gcB = gnB;
    __syncthreads();                               // S1: gates ready
    if (tid < 128) {
      float i_ = sigf(gbuf[tid]);
      float f_ = sigf(gbuf[128 + tid]);
      float g_ = tanhf(gbuf[256 + tid]);
      float o_ = sigf(gbuf[384 + tid]);
      float cc = f_ * creg + i_ * g_;
      creg = cc;
      float h2 = tanhf(o_ * tanhf(cc));            // extra tanh on hidden state
      hallm[((size_t)t * B_ + b) * 128 + tid] = bf16c(h2);
      float hp = __shfl_xor(h2, 1);
      if ((tid & 1) == 0) hbuf[tid >> 1] = pk16(h2, hp);
    }
    __syncthreads();                               // S2: h_t staged
  }
}

__device__ __forceinline__ void mod_body64s(
    const float* __restrict__ gx, const unsigned int* __restrict__ wk,
    int b, unsigned short* __restrict__ hallm, unsigned int* smem) {
  float* gbuf = (float*)smem;          // 256 f32
  unsigned int* hbuf = smem + 512;     // 32 u32
  const int tid = threadIdx.x;
  uint4 wr[8];
  {
    const uint4* wp = reinterpret_cast<const uint4*>(wk + (size_t)tid * 32);
#pragma unroll
    for (int j = 0; j < 8; j++) wr[j] = wp[j];
  }
  if (tid < 32) hbuf[tid] = 0u;
  float creg = 0.f;
  __syncthreads();
  const uint4* h4 = reinterpret_cast<const uint4*>(hbuf);
  const float* gp = gx + (size_t)b * 256 + tid;
  float gc = gp[0];
  for (int t = 0; t < T_; t++) {
    float gn = (t + 1 < T_) ? gp[(size_t)(t + 1) * B_ * 256] : 0.f;
    float a0 = 0.f, a1 = 0.f, a2 = 0.f, a3 = 0.f;
#pragma unroll
    for (int j = 0; j < 8; j++) {
      uint4 hv = h4[j];
      a0 = fdot2f(wr[j].x, hv.x, a0);
      a1 = fdot2f(wr[j].y, hv.y, a1);
      a2 = fdot2f(wr[j].z, hv.z, a2);
      a3 = fdot2f(wr[j].w, hv.w, a3);
    }
    gbuf[tid] = (a0 + a1) + (a2 + a3) + gc;
    gc = gn;
    __syncthreads();                               // S1
    if (tid < 64) {
      float i_ = sigf(gbuf[tid]);
      float f_ = sigf(gbuf[64 + tid]);
      float g_ = tanhf(gbuf[128 + tid]);
      float o_ = sigf(gbuf[192 + tid]);
      float cc = f_ * creg + i_ * g_;
      creg = cc;
      float h2 = tanhf(o_ * tanhf(cc));
      hallm[((size_t)t * B_ + b) * 64 + tid] = bf16c(h2);
      float hp = __shfl_xor(h2, 1);
      if ((tid & 1) == 0) hbuf[tid >> 1] = pk16(h2, hp);
    }
    __syncthreads();                               // S2
  }
}

__global__ __launch_bounds__(256)
__attribute__((amdgpu_waves_per_eu(2, 3)))
void mod_scan(ModScanArgs a, unsigned short* __restrict__ hm_unused) {
  __shared__ __align__(16) unsigned int smem[576];   // gbuf(512) | hbuf(64)
  const int blk = blockIdx.x;
  if (blk < 512) {
    const int mi = blk >> 8, b = blk & 255;
    mod_body128s(mi ? a.gx2 : a.gx0, mi ? a.wk2 : a.wk0, b,
                 mi ? a.hm2 : a.hm0, smem);
  } else {
    mod_body64s(a.gx1, a.wk1, blk - 512, a.hm1, smem);
  }
}

// ---------------------------------------------------------------------------
// dlg_recur: 1024 threads (16 waves), ONE gate row per thread.
// Design-for-the-128-VGPR-budget (rounds 8-10 lesson: the allocator will not
// exceed 128 arch VGPRs for this kernel shape regardless of launch_bounds /
// waves_per_eu / asm pins — it spills instead). Per-thread weights are now
// 96 packed u32 (pairs 0..95) + 32 pairs in LDS: 96 + ~30 working regs fits
// the 128 budget NATURALLY, so weights stay genuinely register-resident.
// 16 waves = 4 waves/SIMD also doubles latency hiding for the LDS broadcasts.
// ---------------------------------------------------------------------------
#define DLG_LDS_BYTES (131072 + 4096 + 512)

__global__ __launch_bounds__(1024) void dlg_recur(
    const float* __restrict__ gxd, const unsigned int* __restrict__ wpk,
    const unsigned int* __restrict__ wldsg, float* __restrict__ hall) {
  extern __shared__ char smem[];
  unsigned int* wl = (unsigned int*)smem;                       // [8][1024][4]
  float* gbuf = (float*)(smem + 131072);                        // [1024]
  _Float16* hbuf_h = (_Float16*)(smem + 131072 + 4096);         // [256]
  const uint4* hbuf4 = (const uint4*)hbuf_h;                    // [32]
  const uint4* wl4 = (const uint4*)wl;
  const int tid = threadIdx.x;
  const int b = blockIdx.x;

  for (int i = tid; i < 32768; i += 1024) wl[i] = wldsg[i];
  unsigned int wr[96];                    // gate row `tid`, pairs 0..95
  {
    const uint4* p0 = reinterpret_cast<const uint4*>(wpk + (size_t)tid * 96);
#pragma unroll
    for (int j = 0; j < 24; j++) {
      uint4 v0 = p0[j];
      wr[4 * j + 0] = v0.x; wr[4 * j + 1] = v0.y;
      wr[4 * j + 2] = v0.z; wr[4 * j + 3] = v0.w;
    }
  }
  if (tid < 32) reinterpret_cast<uint4*>(const_cast<_Float16*>(hbuf_h))[tid] = uint4{0, 0, 0, 0};
  float creg = 0.f;
  __syncthreads();

  const float* gbase = gxd + (size_t)b * 1024 + tid;
  float gc = gbase[0];
  for (int t = 0; t < T_; t++) {
    float gn = (t + 1 < T_) ? gbase[(size_t)(t + 1) * B_ * 1024] : 0.f;
    float a0 = 0.f, a1 = 0.f, a2 = 0.f, a3 = 0.f;
#pragma unroll
    for (int j = 0; j < 24; j++) {          // pairs 0..95 (registers)
      uint4 hv = hbuf4[j];
      a0 = fdot2f(wr[4 * j + 0], hv.x, a0);
      a1 = fdot2f(wr[4 * j + 1], hv.y, a1);
      a2 = fdot2f(wr[4 * j + 2], hv.z, a2);
      a3 = fdot2f(wr[4 * j + 3], hv.w, a3);
    }
#pragma unroll
    for (int jj = 0; jj < 8; jj++) {        // pairs 96..127 (LDS, b128)
      uint4 hv = hbuf4[24 + jj];
      uint4 wa = wl4[jj * 1024 + tid];
      a0 = fdot2f(wa.x, hv.x, a0);
      a1 = fdot2f(wa.y, hv.y, a1);
      a2 = fdot2f(wa.z, hv.z, a2);
      a3 = fdot2f(wa.w, hv.w, a3);
    }
    gbuf[tid] = (a0 + a1) + (a2 + a3) + gc;
    gc = gn;
    __syncthreads();                        // S1: gates ready
    if (tid < DH_) {
      float i_ = sigf(gbuf[tid]);
      float f_ = sigf(gbuf[DH_ + tid]);
      float g_ = tanhf(gbuf[2 * DH_ + tid]);
      float o_ = sigf(gbuf[3 * DH_ + tid]);
      float c2 = f_ * creg + i_ * g_;
      creg = c2;
      float h2 = o_ * tanhf(c2);
      hall[((size_t)t * B_ + b) * DH_ + tid] = h2;
      hbuf_h[tid] = (_Float16)h2;
    }
    __syncthreads();                        // S2: h_t staged
  }
}

// ---------------------------------------------------------------------------
// out_head: fc_out + tanh + smax + log_softmax (unchanged).
// ---------------------------------------------------------------------------
__global__ __launch_bounds__(256) void out_head(
    const float* __restrict__ hall, const float* __restrict__ fcow,
    const float* __restrict__ fcob, const float* __restrict__ smw,
    const float* __restrict__ smb, float* __restrict__ out) {
  __shared__ __align__(16) float h_lds[16][260];
  __shared__ __align__(16) float fco[16][132];
  __shared__ float lg[16][6];
  const int tid = threadIdx.x;
  const int m0 = blockIdx.x * 16;
  {
    const float* src = hall + (size_t)m0 * DH_;
    for (int e = tid; e < 1024; e += 256) {
      float4 v = reinterpret_cast<const float4*>(src)[e];
      const int r = e >> 6, k = (e & 63) * 4;
      *reinterpret_cast<float4*>(&h_lds[r][k]) = v;
    }
  }
  __syncthreads();
  {
    const int f = tid & 127, half = tid >> 7;
    float acc[8];
    const float fb = fcob[f];
#pragma unroll
    for (int r = 0; r < 8; r++) acc[r] = fb;
    const float* wrow = fcow + (size_t)f * DH_;
    for (int k = 0; k < DH_; k += 4) {
      float4 w4 = *reinterpret_cast<const float4*>(wrow + k);
#pragma unroll
      for (int r = 0; r < 8; r++)
        acc[r] += dot4(w4, *reinterpret_cast<const float4*>(&h_lds[half * 8 + r][k]));
    }
#pragma unroll
    for (int r = 0; r < 8; r++) fco[half * 8 + r][f] = tanhf(acc[r]);
  }
  __syncthreads();
  if (tid < 96) {
    const int r = tid / 6, cc = tid % 6;
    float a = smb[cc];
    const float* sw = smw + cc * 128;
#pragma unroll 4
    for (int k = 0; k < 128; k++) a += sw[k] * fco[r][k];
    lg[r][cc] = a;
  }
  __syncthreads();
  if (tid < 16) {
    const int m = m0 + tid;
    const int t = m >> 8, b = m & 255;
    float mx = lg[tid][0];
#pragma unroll
    for (int cc = 1; cc < 6; cc++) mx = fmaxf(mx, lg[tid][cc]);
    float ssum = 0.f;
#pragma unroll
    for (int cc = 0; cc < 6; cc++) ssum += __expf(lg[tid][cc] - mx);
    float lse = mx + logf(ssum);
#pragma unroll
    for (int cc = 0; cc < 6; cc++)
      out[((size_t)b * T_ + t) * 6 + cc] = lg[tid][cc] - lse;
  }
}

// ---------------------------------------------------------------------------
extern "C" void kernel_launch(void* const* d_in, const int* in_sizes, int n_in,
                              void* d_out, int out_size, void* d_ws, size_t ws_size,
                              hipStream_t stream) {
  const float* mod0  = (const float*)d_in[0];
  const float* mod1  = (const float*)d_in[1];
  const float* mod2  = (const float*)d_in[2];
  const float* umask = (const float*)d_in[3];
  const float* w_ih0 = (const float*)d_in[4];
  const float* w_hh0 = (const float*)d_in[5];
  const float* b_ih0 = (const float*)d_in[6];
  const float* b_hh0 = (const float*)d_in[7];
  const float* fc_w0 = (const float*)d_in[8];
  const float* fc_b0 = (const float*)d_in[9];
  const float* w_ih1 = (const float*)d_in[10];
  const float* w_hh1 = (const float*)d_in[11];
  const float* b_ih1 = (const float*)d_in[12];
  const float* b_hh1 = (const float*)d_in[13];
  const float* fc_w1 = (const float*)d_in[14];
  const float* fc_b1 = (const float*)d_in[15];
  const float* w_ih2 = (const float*)d_in[16];
  const float* w_hh2 = (const float*)d_in[17];
  const float* b_ih2 = (const float*)d_in[18];
  const float* b_hh2 = (const float*)d_in[19];
  const float* fc_w2 = (const float*)d_in[20];
  const float* fc_b2 = (const float*)d_in[21];
  const float* w_ih_d = (const float*)d_in[22];
  const float* w_hh_d = (const float*)d_in[23];
  const float* b_ih_d = (const float*)d_in[24];
  const float* b_hh_d = (const float*)d_in[25];
  const float* fco_w  = (const float*)d_in[26];
  const float* fco_b  = (const float*)d_in[27];
  const float* sm_w   = (const float*)d_in[28];
  const float* sm_b   = (const float*)d_in[29];

  // workspace layout (float units):
  //   [0, M*1280): gx0|gx1|gx2 -> reused as gxd [0,M*1024)
  //   [M*1024, M*1280): hallm0|hallm2|hallm1 (bf16) -> later hall (fp32)
  float* ws    = (float*)d_ws;
  float* gx0   = ws;                                  // M*512
  float* gx1   = gx0 + (size_t)M_ * 512;              // M*256
  float* gx2   = gx1 + (size_t)M_ * 256;              // M*512
  float* gxd   = ws;                                  // M*1024 (reuse)
  float* hall  = ws + (size_t)M_ * 1024;              // M*256 fp32
  unsigned short* hm0 = (unsigned short*)(ws + (size_t)M_ * 1024);  // M*128 bf16
  unsigned short* hm2 = hm0 + (size_t)M_ * 128;                     // M*128 bf16
  unsigned short* hm1 = hm2 + (size_t)M_ * 128;                     // M*64 bf16
  unsigned short* dfeat_h = (unsigned short*)(ws + (size_t)M_ * 1280);  // M*256 bf16
  float* tail  = ws + (size_t)M_ * 1408;
  float* biasd = tail;                                // 1024
  float* bias0 = biasd + 1024;                        // 512
  float* bias1 = bias0 + 512;                         // 256
  float* bias2 = bias1 + 256;                         // 512
  unsigned int* wpk   = (unsigned int*)(bias2 + 512); // 1024*96
  unsigned int* wldsg = wpk + 1024 * 96;              // 32768
  unsigned int* wpk0  = wldsg + 32768;                // 512*64
  unsigned int* wpk1  = wpk0 + 512 * 64;              // 256*32
  unsigned int* wpk2  = wpk1 + 256 * 32;              // 512*64
  unsigned short* w0b = (unsigned short*)(wpk2 + 512 * 64);  // 512*320
  unsigned short* w1b = w0b + 512 * 320;                     // 256*128
  unsigned short* w2b = w1b + 256 * 128;                     // 512*512
  unsigned short* wdb = w2b + 512 * 512;                     // 1024*256
  unsigned short* fcw0b = wdb + 1024 * 256;                  // 128*128
  unsigned short* fcw1b = fcw0b + 128 * 128;                 // 64*64
  unsigned short* fcw2b = fcw1b + 64 * 64;                   // 128*128

  prep_kernel<<<256, 256, 0, stream>>>(w_ih_d, w_hh_d, b_ih_d, b_hh_d,
      b_ih0, b_hh0, b_ih1, b_hh1, b_ih2, b_hh2,
      w_hh0, w_hh1, w_hh2, w_ih0, w_ih1, w_ih2, fc_w0, fc_w1, fc_w2,
      dfeat_h, biasd, bias0, bias1, bias2, wpk, wldsg,
      wpk0, wpk1, wpk2, w0b, w1b, w2b, wdb, fcw0b, fcw1b, fcw2b);

  // input projections (bf16 MFMA)
  mfma_gemm<false><<<8 * 512, 256, 0, stream>>>(mod0, w0b, bias0, umask, gx0, 300, 320, 512);
  mfma_gemm<false><<<4 * 512, 256, 0, stream>>>(mod1, w1b, bias1, umask, gx1, 100, 128, 256);
  mfma_gemm<false><<<8 * 512, 256, 0, stream>>>(mod2, w2b, bias2, umask, gx2, 512, 512, 512);

  // fused modality scans (FC evicted; h -> hallm bf16)
  ModScanArgs a;
  a.gx0 = gx0; a.gx1 = gx1; a.gx2 = gx2;
  a.wk0 = wpk0; a.wk1 = wpk1; a.wk2 = wpk2;
  a.hm0 = hm0; a.hm1 = hm1; a.hm2 = hm2;
  mod_scan<<<768, 256, 0, stream>>>(a, nullptr);

  // FC heads (bf16 MFMA) -> dfeat
  fc_gemm<<<512 * 2, 256, 0, stream>>>(hm0, fcw0b, fc_b0, umask, dfeat_h, 128, 2, 100, 0);
  fc_gemm<<<512 * 1, 256, 0, stream>>>(hm1, fcw1b, fc_b1, umask, dfeat_h, 64, 1, 50, 100);
  fc_gemm<<<512 * 2, 256, 0, stream>>>(hm2, fcw2b, fc_b2, umask, dfeat_h, 128, 2, 100, 150);

  // dialogue input projection (bf16 MFMA, X already bf16)
  mfma_gemm<true><<<16 * 512, 256, 0, stream>>>(dfeat_h, wdb, biasd, nullptr, gxd, 256, 256, 1024);

  hipFuncSetAttribute(reinterpret_cast<const void*>(dlg_recur),
                      hipFuncAttributeMaxDynamicSharedMemorySize, DLG_LDS_BYTES);
  dlg_recur<<<256, 1024, DLG_LDS_BYTES, stream>>>(gxd, wpk, wldsg, hall);

  out_head<<<M_ / 16, 256, 0, stream>>>(hall, fco_w, fco_b, sm_w, sm_b, (float*)d_out);
}

// Round 12
// 888.127 us; speedup vs baseline: 1.0465x; 1.0465x over previous
//
#include <hip/hip_runtime.h>

#define B_ 256
#define T_ 128
#define M_ (B_ * T_)
#define DH_ 256

__device__ __forceinline__ float sigf(float x) { return 1.0f / (1.0f + __expf(-x)); }
__device__ __forceinline__ float dot4(float4 a, float4 b) {
  return a.x * b.x + a.y * b.y + a.z * b.z + a.w * b.w;
}

typedef _Float16 half2v __attribute__((ext_vector_type(2)));
typedef short short8 __attribute__((ext_vector_type(8)));
typedef float f32x4 __attribute__((ext_vector_type(4)));

__device__ __forceinline__ float fdot2f(unsigned int w, unsigned int h, float acc) {
  half2v wv = __builtin_bit_cast(half2v, w);
  half2v hv = __builtin_bit_cast(half2v, h);
#if __has_builtin(__builtin_amdgcn_fdot2)
  return __builtin_amdgcn_fdot2(wv, hv, acc, false);
#else
  return acc + (float)wv[0] * (float)hv[0] + (float)wv[1] * (float)hv[1];
#endif
}
__device__ __forceinline__ unsigned int pk16(float a, float b) {
  unsigned short lo = __builtin_bit_cast(unsigned short, (_Float16)a);
  unsigned short hi = __builtin_bit_cast(unsigned short, (_Float16)b);
  return (unsigned int)lo | ((unsigned int)hi << 16);
}
__device__ __forceinline__ unsigned short bf16c(float x) {  // RNE f32->bf16
  unsigned int u = __builtin_bit_cast(unsigned int, x);
  return (unsigned short)((u + 0x7FFFu + ((u >> 16) & 1u)) >> 16);
}
__device__ __forceinline__ unsigned int bfpk(float a, float b) {
  return (unsigned int)bf16c(a) | ((unsigned int)bf16c(b) << 16);
}
// AGPR staging: "a"-class virtual registers. An asm-PRODUCED value cannot be
// rematerialized as a memory load (rounds 8-11: the pre-RA rematerializer
// demotes load-produced loop-invariant weights to per-step L2 re-reads no
// matter what launch_bounds/waves_per_eu/pins say). awr moves a value into
// the AGPR file; ard (VOLATILE: must not be LICM-hoisted back into VGPRs)
// reads it back each use.
__device__ __forceinline__ unsigned int awr(unsigned int v) {
  unsigned int a;
  asm volatile("v_accvgpr_write_b32 %0, %1" : "=a"(a) : "v"(v));
  return a;
}
__device__ __forceinline__ unsigned int ard(unsigned int a) {
  unsigned int r;
  asm volatile("v_accvgpr_read_b32 %0, %1" : "=v"(r) : "a"(a));
  return r;
}

// ---------------------------------------------------------------------------
// prep: combined biases; bf16 zero-padded GEMM weights (input projections,
// dialogue projection, per-modality FC); fp16-packed recurrent weights
// (dialogue reg/LDS split + modality register rows).
// ---------------------------------------------------------------------------
__global__ void prep_kernel(const float* __restrict__ w_ih_d, const float* __restrict__ w_hh_d,
                            const float* __restrict__ b_ih_d, const float* __restrict__ b_hh_d,
                            const float* __restrict__ b_ih0, const float* __restrict__ b_hh0,
                            const float* __restrict__ b_ih1, const float* __restrict__ b_hh1,
                            const float* __restrict__ b_ih2, const float* __restrict__ b_hh2,
                            const float* __restrict__ w_hh0, const float* __restrict__ w_hh1,
                            const float* __restrict__ w_hh2,
                            const float* __restrict__ w_ih0, const float* __restrict__ w_ih1,
                            const float* __restrict__ w_ih2,
                            const float* __restrict__ fc_w0, const float* __restrict__ fc_w1,
                            const float* __restrict__ fc_w2,
                            unsigned short* __restrict__ dfeat_h,
                            float* __restrict__ biasd, float* __restrict__ bias0,
                            float* __restrict__ bias1, float* __restrict__ bias2,
                            unsigned int* __restrict__ wpk, unsigned int* __restrict__ wldsg,
                            unsigned int* __restrict__ wpk0, unsigned int* __restrict__ wpk1,
                            unsigned int* __restrict__ wpk2,
                            unsigned short* __restrict__ w0b, unsigned short* __restrict__ w1b,
                            unsigned short* __restrict__ w2b, unsigned short* __restrict__ wdb,
                            unsigned short* __restrict__ fcw0b, unsigned short* __restrict__ fcw1b,
                            unsigned short* __restrict__ fcw2b) {
  int idx = blockIdx.x * blockDim.x + threadIdx.x;
  int stride = gridDim.x * blockDim.x;
  // bf16 GEMM weights (K zero-padded to multiple of 32)
  for (int i = idx; i < 512 * 320; i += stride) {
    int r = i / 320, k = i % 320;
    w0b[i] = (k < 300) ? bf16c(w_ih0[(size_t)r * 300 + k]) : (unsigned short)0;
  }
  for (int i = idx; i < 256 * 128; i += stride) {
    int r = i >> 7, k = i & 127;
    w1b[i] = (k < 100) ? bf16c(w_ih1[(size_t)r * 100 + k]) : (unsigned short)0;
  }
  for (int i = idx; i < 512 * 512; i += stride) w2b[i] = bf16c(w_ih2[i]);
  for (int i = idx; i < 1024 * 256; i += stride) {
    int r = i >> 8, k = i & 255;
    wdb[i] = (k < 250) ? bf16c(w_ih_d[(size_t)r * 250 + k]) : (unsigned short)0;
  }
  // FC weights bf16, rows zero-padded to 128/64
  for (int i = idx; i < 128 * 128; i += stride) {
    int f = i >> 7, k = i & 127;
    fcw0b[i] = (f < 100) ? bf16c(fc_w0[(size_t)f * 128 + k]) : (unsigned short)0;
    fcw2b[i] = (f < 100) ? bf16c(fc_w2[(size_t)f * 128 + k]) : (unsigned short)0;
  }
  for (int i = idx; i < 64 * 64; i += stride) {
    int f = i >> 6, k = i & 63;
    fcw1b[i] = (f < 50) ? bf16c(fc_w1[(size_t)f * 64 + k]) : (unsigned short)0;
  }
  for (int i = idx; i < M_ * 6; i += stride)   // zero dfeat_h pad cols 250..255
    dfeat_h[(size_t)(i / 6) * 256 + 250 + (i % 6)] = 0;
  // dialogue recurrent weights fp16: reg part (pairs 0..95), row r = gate row
  for (int i = idx; i < 1024 * 96; i += stride) {
    int r = i / 96, k0 = (i % 96) * 2;
    wpk[i] = pk16(w_hh_d[(size_t)r * 256 + k0], w_hh_d[(size_t)r * 256 + k0 + 1]);
  }
  // dialogue LDS part, b128 layout: i = (jj*1024 + r)*4 + q, pair p = 96+4*jj+q
  for (int i = idx; i < 32768; i += stride) {
    int jj = i >> 12, rem = i & 4095, r = rem >> 2, q = rem & 3;
    int p = 96 + 4 * jj + q;
    wldsg[i] = pk16(w_hh_d[(size_t)r * 256 + 2 * p], w_hh_d[(size_t)r * 256 + 2 * p + 1]);
  }
  // modality recurrent weights (row-major packed pairs)
  for (int i = idx; i < 512 * 64; i += stride) {
    int r = i >> 6, p = (i & 63) * 2;
    wpk0[i] = pk16(w_hh0[(size_t)r * 128 + p], w_hh0[(size_t)r * 128 + p + 1]);
    wpk2[i] = pk16(w_hh2[(size_t)r * 128 + p], w_hh2[(size_t)r * 128 + p + 1]);
  }
  for (int i = idx; i < 256 * 32; i += stride) {
    int r = i >> 5, p = (i & 31) * 2;
    wpk1[i] = pk16(w_hh1[(size_t)r * 64 + p], w_hh1[(size_t)r * 64 + p + 1]);
  }
  for (int i = idx; i < 1024; i += stride) biasd[i] = b_ih_d[i] + b_hh_d[i];
  for (int i = idx; i < 512; i += stride) bias0[i] = b_ih0[i] + b_hh0[i];
  for (int i = idx; i < 256; i += stride) bias1[i] = b_ih1[i] + b_hh1[i];
  for (int i = idx; i < 512; i += stride) bias2[i] = b_ih2[i] + b_hh2[i];
}

// ---------------------------------------------------------------------------
// mfma_gemm: C[m][n] = scale * sum_k X[m][k]*W[n][k] + bias[n], bf16 MFMA.
// (unchanged — verified)
// ---------------------------------------------------------------------------
template <bool XF16>
__global__ __launch_bounds__(256) void mfma_gemm(
    const void* __restrict__ Xv, const unsigned short* __restrict__ Wb,
    const float* __restrict__ bias, const float* __restrict__ umask,
    float* __restrict__ C, int K, int Kp, int N) {
  __shared__ __align__(16) unsigned short Xs[64][40];
  __shared__ __align__(16) unsigned short Ws[64][40];
  const int tid = threadIdx.x;
  const int d = blockIdx.x;
  const int nx = N >> 6;
  const int n0 = ((d % (nx << 3)) >> 3) << 6;
  const int m0 = (((d / (nx << 3)) << 3) + (d & 7)) << 6;
  const int srow = tid >> 2, kq = tid & 3;
  const int w = tid >> 6, lane = tid & 63;
  const int lr = lane & 15, lk = lane >> 4;
  const float* Xf = nullptr;
  const unsigned short* Xh = nullptr;
  if constexpr (XF16) {
    Xh = (const unsigned short*)Xv + (size_t)(m0 + srow) * Kp;
  } else {
    const int t = m0 >> 8, b0 = m0 & 255;
    Xf = (const float*)Xv + ((size_t)(b0 + srow) * T_ + t) * K;
  }
  const unsigned short* Wr = Wb + (size_t)(n0 + srow) * Kp;
  f32x4 acc[4];
#pragma unroll
  for (int j = 0; j < 4; j++) acc[j] = (f32x4){0.f, 0.f, 0.f, 0.f};

  for (int k0 = 0; k0 < Kp; k0 += 32) {
    uint4 xa;
    const int kk = k0 + kq * 8;
    if constexpr (XF16) {
      xa = *reinterpret_cast<const uint4*>(Xh + kk);
    } else {
      float4 va = (kk + 3 < K) ? *reinterpret_cast<const float4*>(Xf + kk)
                               : make_float4(0.f, 0.f, 0.f, 0.f);
      float4 vb = (kk + 7 < K) ? *reinterpret_cast<const float4*>(Xf + kk + 4)
                               : make_float4(0.f, 0.f, 0.f, 0.f);
      xa.x = bfpk(va.x, va.y); xa.y = bfpk(va.z, va.w);
      xa.z = bfpk(vb.x, vb.y); xa.w = bfpk(vb.z, vb.w);
    }
    uint4 wv = *reinterpret_cast<const uint4*>(Wr + kk);
    __syncthreads();
    *reinterpret_cast<uint4*>(&Xs[srow][kq * 8]) = xa;
    *reinterpret_cast<uint4*>(&Ws[srow][kq * 8]) = wv;
    __syncthreads();
    short8 af = *reinterpret_cast<const short8*>(&Xs[w * 16 + lr][lk * 8]);
#pragma unroll
    for (int j = 0; j < 4; j++) {
      short8 bf = *reinterpret_cast<const short8*>(&Ws[j * 16 + lr][lk * 8]);
      acc[j] = __builtin_amdgcn_mfma_f32_16x16x32_bf16(af, bf, acc[j], 0, 0, 0);
    }
  }
#pragma unroll
  for (int j = 0; j < 4; j++) {
    const int col = n0 + j * 16 + lr;
    const float bv = bias[col];
#pragma unroll
    for (int r = 0; r < 4; r++) {
      const int mrow = m0 + w * 16 + lk * 4 + r;
      float um = 1.0f;
      if constexpr (!XF16)
        um = umask[((m0 & 255) + w * 16 + lk * 4 + r) * T_ + (m0 >> 8)];
      C[(size_t)mrow * N + col] = acc[j][r] * um + bv;
    }
  }
}

// ---------------------------------------------------------------------------
// fc_gemm: per-modality FC head as bf16 MFMA GEMM (out of the scan).
// ---------------------------------------------------------------------------
__global__ __launch_bounds__(256) void fc_gemm(
    const unsigned short* __restrict__ Xh, const unsigned short* __restrict__ Wb,
    const float* __restrict__ fcb, const float* __restrict__ umask,
    unsigned short* __restrict__ dfeat_h, int Kp, int nx, int F, int col0) {
  __shared__ __align__(16) unsigned short Xs[64][40];
  __shared__ __align__(16) unsigned short Ws[64][40];
  const int tid = threadIdx.x;
  const int n0 = (blockIdx.x % nx) * 64;
  const int m0 = (blockIdx.x / nx) * 64;
  const int srow = tid >> 2, kq = tid & 3;
  const int w = tid >> 6, lane = tid & 63;
  const int lr = lane & 15, lk = lane >> 4;
  const unsigned short* Xp = Xh + (size_t)(m0 + srow) * Kp;
  const unsigned short* Wr = Wb + (size_t)(n0 + srow) * Kp;
  f32x4 acc[4];
#pragma unroll
  for (int j = 0; j < 4; j++) acc[j] = (f32x4){0.f, 0.f, 0.f, 0.f};
  for (int k0 = 0; k0 < Kp; k0 += 32) {
    const int kk = k0 + kq * 8;
    uint4 xa = *reinterpret_cast<const uint4*>(Xp + kk);
    uint4 wv = *reinterpret_cast<const uint4*>(Wr + kk);
    __syncthreads();
    *reinterpret_cast<uint4*>(&Xs[srow][kq * 8]) = xa;
    *reinterpret_cast<uint4*>(&Ws[srow][kq * 8]) = wv;
    __syncthreads();
    short8 af = *reinterpret_cast<const short8*>(&Xs[w * 16 + lr][lk * 8]);
#pragma unroll
    for (int j = 0; j < 4; j++) {
      short8 bf = *reinterpret_cast<const short8*>(&Ws[j * 16 + lr][lk * 8]);
      acc[j] = __builtin_amdgcn_mfma_f32_16x16x32_bf16(af, bf, acc[j], 0, 0, 0);
    }
  }
#pragma unroll
  for (int j = 0; j < 4; j++) {
    const int coln = n0 + j * 16 + lr;
    const float bv = (coln < F) ? fcb[coln] : 0.f;
#pragma unroll
    for (int r = 0; r < 4; r++) {
      const int mrow = m0 + w * 16 + lk * 4 + r;
      if (coln < F) {
        const int t = mrow >> 8, b = mrow & 255;
        float um = umask[b * T_ + t];
        dfeat_h[(size_t)mrow * 256 + col0 + coln] = bf16c(tanhf(acc[j][r] + bv) * um);
      }
    }
  }
}

// ---------------------------------------------------------------------------
// mod_scan: fused modality LSTM scans (FC evicted; h -> hallm bf16).
// EXACT round-8 configuration (measured good): waves_per_eu(2,3), no pins.
// ---------------------------------------------------------------------------
struct ModScanArgs {
  const float* gx0; const float* gx1; const float* gx2;
  const unsigned int* wk0; const unsigned int* wk1; const unsigned int* wk2;
  unsigned short* hm0; unsigned short* hm1; unsigned short* hm2;
};

__device__ __forceinline__ void mod_body128s(
    const float* __restrict__ gx, const unsigned int* __restrict__ wk,
    int b, unsigned short* __restrict__ hallm, unsigned int* smem) {
  float* gbuf = (float*)smem;          // 512 f32
  unsigned int* hbuf = smem + 512;     // 64 u32
  const int tid = threadIdx.x;
  uint4 wrA[16], wrB[16];
  {
    const uint4* wpA = reinterpret_cast<const uint4*>(wk + (size_t)tid * 64);
    const uint4* wpB = reinterpret_cast<const uint4*>(wk + (size_t)(tid + 256) * 64);
#pragma unroll
    for (int j = 0; j < 16; j++) { wrA[j] = wpA[j]; wrB[j] = wpB[j]; }
  }
  if (tid < 64) hbuf[tid] = 0u;
  float creg = 0.f;
  __syncthreads();
  const uint4* h4 = reinterpret_cast<const uint4*>(hbuf);
  const float* gp = gx + (size_t)b * 512 + tid;
  float gcA = gp[0], gcB = gp[256];
  for (int t = 0; t < T_; t++) {
    float gnA = 0.f, gnB = 0.f;
    if (t + 1 < T_) {
      gnA = gp[(size_t)(t + 1) * B_ * 512];
      gnB = gp[(size_t)(t + 1) * B_ * 512 + 256];
    }
    float a0 = 0.f, a1 = 0.f, a2 = 0.f, a3 = 0.f;
    float d0 = 0.f, d1 = 0.f, d2 = 0.f, d3 = 0.f;
#pragma unroll
    for (int j = 0; j < 16; j++) {
      uint4 hv = h4[j];
      a0 = fdot2f(wrA[j].x, hv.x, a0);
      a1 = fdot2f(wrA[j].y, hv.y, a1);
      a2 = fdot2f(wrA[j].z, hv.z, a2);
      a3 = fdot2f(wrA[j].w, hv.w, a3);
      d0 = fdot2f(wrB[j].x, hv.x, d0);
      d1 = fdot2f(wrB[j].y, hv.y, d1);
      d2 = fdot2f(wrB[j].z, hv.z, d2);
      d3 = fdot2f(wrB[j].w, hv.w, d3);
    }
    gbuf[tid] = (a0 + a1) + (a2 + a3) + gcA;      // gx includes bias + umask'd x
    gbuf[tid + 256] = (d0 + d1) + (d2 + d3) + gcB;
    gcA = gnA; gcB = gnB;
    __syncthreads();                               // S1: gates ready
    if (tid < 128) {
      float i_ = sigf(gbuf[tid]);
      float f_ = sigf(gbuf[128 + tid]);
      float g_ = tanhf(gbuf[256 + tid]);
      float o_ = sigf(gbuf[384 + tid]);
      float cc = f_ * creg + i_ * g_;
      creg = cc;
      float h2 = tanhf(o_ * tanhf(cc));            // extra tanh on hidden state
      hallm[((size_t)t * B_ + b) * 128 + tid] = bf16c(h2);
      float hp = __shfl_xor(h2, 1);
      if ((tid & 1) == 0) hbuf[tid >> 1] = pk16(h2, hp);
    }
    __syncthreads();                               // S2: h_t staged
  }
}

__device__ __forceinline__ void mod_body64s(
    const float* __restrict__ gx, const unsigned int* __restrict__ wk,
    int b, unsigned short* __restrict__ hallm, unsigned int* smem) {
  float* gbuf = (float*)smem;          // 256 f32
  unsigned int* hbuf = smem + 512;     // 32 u32
  const int tid = threadIdx.x;
  uint4 wr[8];
  {
    const uint4* wp = reinterpret_cast<const uint4*>(wk + (size_t)tid * 32);
#pragma unroll
    for (int j = 0; j < 8; j++) wr[j] = wp[j];
  }
  if (tid < 32) hbuf[tid] = 0u;
  float creg = 0.f;
  __syncthreads();
  const uint4* h4 = reinterpret_cast<const uint4*>(hbuf);
  const float* gp = gx + (size_t)b * 256 + tid;
  float gc = gp[0];
  for (int t = 0; t < T_; t++) {
    float gn = (t + 1 < T_) ? gp[(size_t)(t + 1) * B_ * 256] : 0.f;
    float a0 = 0.f, a1 = 0.f, a2 = 0.f, a3 = 0.f;
#pragma unroll
    for (int j = 0; j < 8; j++) {
      uint4 hv = h4[j];
      a0 = fdot2f(wr[j].x, hv.x, a0);
      a1 = fdot2f(wr[j].y, hv.y, a1);
      a2 = fdot2f(wr[j].z, hv.z, a2);
      a3 = fdot2f(wr[j].w, hv.w, a3);
    }
    gbuf[tid] = (a0 + a1) + (a2 + a3) + gc;
    gc = gn;
    __syncthreads();                               // S1
    if (tid < 64) {
      float i_ = sigf(gbuf[tid]);
      float f_ = sigf(gbuf[64 + tid]);
      float g_ = tanhf(gbuf[128 + tid]);
      float o_ = sigf(gbuf[192 + tid]);
      float cc = f_ * creg + i_ * g_;
      creg = cc;
      float h2 = tanhf(o_ * tanhf(cc));
      hallm[((size_t)t * B_ + b) * 64 + tid] = bf16c(h2);
      float hp = __shfl_xor(h2, 1);
      if ((tid & 1) == 0) hbuf[tid >> 1] = pk16(h2, hp);
    }
    __syncthreads();                               // S2
  }
}

__global__ __launch_bounds__(256)
__attribute__((amdgpu_waves_per_eu(2, 3)))
void mod_scan(ModScanArgs a, unsigned short* __restrict__ hm_unused) {
  __shared__ __align__(16) unsigned int smem[576];   // gbuf(512) | hbuf(64)
  const int blk = blockIdx.x;
  if (blk < 512) {
    const int mi = blk >> 8, b = blk & 255;
    mod_body128s(mi ? a.gx2 : a.gx0, mi ? a.wk2 : a.wk0, b,
                 mi ? a.hm2 : a.hm0, smem);
  } else {
    mod_body64s(a.gx1, a.wk1, blk - 512, a.hm1, smem);
  }
}

// ---------------------------------------------------------------------------
// dlg_recur: round-8 512-thread structure, weights in AGPRs.
// 192 weight words/thread live in the AGPR half of the unified file
// (pressure: 192a + ~50v = 242 <= 256-per-wave budget at 2 waves/SIMD, which
// the 132 KB LDS already forces). awr/ard asm makes the values
// non-rematerializable — closing the demotion path that kept VGPR_Count
// stuck at 128 and the kernel L2-BW-bound (~31 TB/s) in rounds 8-11.
// ---------------------------------------------------------------------------
#define DLG_LDS_BYTES (131072 + 4096 + 512)

__global__ __launch_bounds__(512)
__attribute__((amdgpu_waves_per_eu(2, 2)))
void dlg_recur(
    const float* __restrict__ gxd, const unsigned int* __restrict__ wpk,
    const unsigned int* __restrict__ wldsg, float* __restrict__ hall) {
  extern __shared__ char smem[];
  unsigned int* wl = (unsigned int*)smem;                       // [8][1024][4]
  float* gbuf = (float*)(smem + 131072);                        // [1024]
  _Float16* hbuf_h = (_Float16*)(smem + 131072 + 4096);         // [256]
  const uint4* hbuf4 = (const uint4*)hbuf_h;                    // [32]
  const uint4* wl4 = (const uint4*)wl;
  const int tid = threadIdx.x;
  const int b = blockIdx.x;

  for (int i = tid; i < 32768; i += 512) wl[i] = wldsg[i];
  // gate rows tid and tid+512, pairs 0..95 -> AGPRs
  unsigned int wa0[96], wa1[96];
  {
    const uint4* p0 = reinterpret_cast<const uint4*>(wpk + (size_t)tid * 96);
    const uint4* p1 = reinterpret_cast<const uint4*>(wpk + (size_t)(tid + 512) * 96);
#pragma unroll
    for (int j = 0; j < 24; j++) {
      uint4 v0 = p0[j], v1 = p1[j];
      wa0[4 * j + 0] = awr(v0.x); wa0[4 * j + 1] = awr(v0.y);
      wa0[4 * j + 2] = awr(v0.z); wa0[4 * j + 3] = awr(v0.w);
      wa1[4 * j + 0] = awr(v1.x); wa1[4 * j + 1] = awr(v1.y);
      wa1[4 * j + 2] = awr(v1.z); wa1[4 * j + 3] = awr(v1.w);
    }
  }
  if (tid < 32) reinterpret_cast<uint4*>(const_cast<_Float16*>(hbuf_h))[tid] = uint4{0, 0, 0, 0};
  float creg = 0.f;
  __syncthreads();

  const float* gbase = gxd + (size_t)b * 1024 + tid;
  float gc0 = gbase[0], gc1 = gbase[512];
  for (int t = 0; t < T_; t++) {
    float gn0 = 0.f, gn1 = 0.f;
    if (t + 1 < T_) {
      gn0 = gbase[(size_t)(t + 1) * B_ * 1024];
      gn1 = gbase[(size_t)(t + 1) * B_ * 1024 + 512];
    }
    float a0 = 0.f, a1 = 0.f;
#pragma unroll
    for (int j = 0; j < 24; j++) {          // pairs 0..95 (AGPR-resident)
      uint4 hv = hbuf4[j];
      a0 = fdot2f(ard(wa0[4 * j + 0]), hv.x, a0); a1 = fdot2f(ard(wa1[4 * j + 0]), hv.x, a1);
      a0 = fdot2f(ard(wa0[4 * j + 1]), hv.y, a0); a1 = fdot2f(ard(wa1[4 * j + 1]), hv.y, a1);
      a0 = fdot2f(ard(wa0[4 * j + 2]), hv.z, a0); a1 = fdot2f(ard(wa1[4 * j + 2]), hv.z, a1);
      a0 = fdot2f(ard(wa0[4 * j + 3]), hv.w, a0); a1 = fdot2f(ard(wa1[4 * j + 3]), hv.w, a1);
    }
#pragma unroll
    for (int jj = 0; jj < 8; jj++) {        // pairs 96..127 (LDS, b128)
      uint4 hv = hbuf4[24 + jj];
      uint4 wa = wl4[jj * 1024 + tid];
      uint4 wc = wl4[jj * 1024 + tid + 512];
      a0 = fdot2f(wa.x, hv.x, a0); a1 = fdot2f(wc.x, hv.x, a1);
      a0 = fdot2f(wa.y, hv.y, a0); a1 = fdot2f(wc.y, hv.y, a1);
      a0 = fdot2f(wa.z, hv.z, a0); a1 = fdot2f(wc.z, hv.z, a1);
      a0 = fdot2f(wa.w, hv.w, a0); a1 = fdot2f(wc.w, hv.w, a1);
    }
    gbuf[tid] = a0 + gc0;
    gbuf[tid + 512] = a1 + gc1;
    __syncthreads();
    if (tid < DH_) {
      float i_ = sigf(gbuf[tid]);
      float f_ = sigf(gbuf[DH_ + tid]);
      float g_ = tanhf(gbuf[2 * DH_ + tid]);
      float o_ = sigf(gbuf[3 * DH_ + tid]);
      float c2 = f_ * creg + i_ * g_;
      creg = c2;
      float h2 = o_ * tanhf(c2);
      hall[((size_t)t * B_ + b) * DH_ + tid] = h2;
      hbuf_h[tid] = (_Float16)h2;
    }
    gc0 = gn0; gc1 = gn1;
    __syncthreads();
  }
}

// ---------------------------------------------------------------------------
// out_head: fc_out + tanh + smax + log_softmax (unchanged).
// ---------------------------------------------------------------------------
__global__ __launch_bounds__(256) void out_head(
    const float* __restrict__ hall, const float* __restrict__ fcow,
    const float* __restrict__ fcob, const float* __restrict__ smw,
    const float* __restrict__ smb, float* __restrict__ out) {
  __shared__ __align__(16) float h_lds[16][260];
  __shared__ __align__(16) float fco[16][132];
  __shared__ float lg[16][6];
  const int tid = threadIdx.x;
  const int m0 = blockIdx.x * 16;
  {
    const float* src = hall + (size_t)m0 * DH_;
    for (int e = tid; e < 1024; e += 256) {
      float4 v = reinterpret_cast<const float4*>(src)[e];
      const int r = e >> 6, k = (e & 63) * 4;
      *reinterpret_cast<float4*>(&h_lds[r][k]) = v;
    }
  }
  __syncthreads();
  {
    const int f = tid & 127, half = tid >> 7;
    float acc[8];
    const float fb = fcob[f];
#pragma unroll
    for (int r = 0; r < 8; r++) acc[r] = fb;
    const float* wrow = fcow + (size_t)f * DH_;
    for (int k = 0; k < DH_; k += 4) {
      float4 w4 = *reinterpret_cast<const float4*>(wrow + k);
#pragma unroll
      for (int r = 0; r < 8; r++)
        acc[r] += dot4(w4, *reinterpret_cast<const float4*>(&h_lds[half * 8 + r][k]));
    }
#pragma unroll
    for (int r = 0; r < 8; r++) fco[half * 8 + r][f] = tanhf(acc[r]);
  }
  __syncthreads();
  if (tid < 96) {
    const int r = tid / 6, cc = tid % 6;
    float a = smb[cc];
    const float* sw = smw + cc * 128;
#pragma unroll 4
    for (int k = 0; k < 128; k++) a += sw[k] * fco[r][k];
    lg[r][cc] = a;
  }
  __syncthreads();
  if (tid < 16) {
    const int m = m0 + tid;
    const int t = m >> 8, b = m & 255;
    float mx = lg[tid][0];
#pragma unroll
    for (int cc = 1; cc < 6; cc++) mx = fmaxf(mx, lg[tid][cc]);
    float ssum = 0.f;
#pragma unroll
    for (int cc = 0; cc < 6; cc++) ssum += __expf(lg[tid][cc] - mx);
    float lse = mx + logf(ssum);
#pragma unroll
    for (int cc = 0; cc < 6; cc++)
      out[((size_t)b * T_ + t) * 6 + cc] = lg[tid][cc] - lse;
  }
}

// ---------------------------------------------------------------------------
extern "C" void kernel_launch(void* const* d_in, const int* in_sizes, int n_in,
                              void* d_out, int out_size, void* d_ws, size_t ws_size,
                              hipStream_t stream) {
  const float* mod0  = (const float*)d_in[0];
  const float* mod1  = (const float*)d_in[1];
  const float* mod2  = (const float*)d_in[2];
  const float* umask = (const float*)d_in[3];
  const float* w_ih0 = (const float*)d_in[4];
  const float* w_hh0 = (const float*)d_in[5];
  const float* b_ih0 = (const float*)d_in[6];
  const float* b_hh0 = (const float*)d_in[7];
  const float* fc_w0 = (const float*)d_in[8];
  const float* fc_b0 = (const float*)d_in[9];
  const float* w_ih1 = (const float*)d_in[10];
  const float* w_hh1 = (const float*)d_in[11];
  const float* b_ih1 = (const float*)d_in[12];
  const float* b_hh1 = (const float*)d_in[13];
  const float* fc_w1 = (const float*)d_in[14];
  const float* fc_b1 = (const float*)d_in[15];
  const float* w_ih2 = (const float*)d_in[16];
  const float* w_hh2 = (const float*)d_in[17];
  const float* b_ih2 = (const float*)d_in[18];
  const float* b_hh2 = (const float*)d_in[19];
  const float* fc_w2 = (const float*)d_in[20];
  const float* fc_b2 = (const float*)d_in[21];
  const float* w_ih_d = (const float*)d_in[22];
  const float* w_hh_d = (const float*)d_in[23];
  const float* b_ih_d = (const float*)d_in[24];
  const float* b_hh_d = (const float*)d_in[25];
  const float* fco_w  = (const float*)d_in[26];
  const float* fco_b  = (const float*)d_in[27];
  const float* sm_w   = (const float*)d_in[28];
  const float* sm_b   = (const float*)d_in[29];

  // workspace layout (float units):
  //   [0, M*1280): gx0|gx1|gx2 -> reused as gxd [0,M*1024)
  //   [M*1024, M*1280): hallm0|hallm2|hallm1 (bf16) -> later hall (fp32)
  float* ws    = (float*)d_ws;
  float* gx0   = ws;                                  // M*512
  float* gx1   = gx0 + (size_t)M_ * 512;              // M*256
  float* gx2   = gx1 + (size_t)M_ * 256;              // M*512
  float* gxd   = ws;                                  // M*1024 (reuse)
  float* hall  = ws + (size_t)M_ * 1024;              // M*256 fp32
  unsigned short* hm0 = (unsigned short*)(ws + (size_t)M_ * 1024);  // M*128 bf16
  unsigned short* hm2 = hm0 + (size_t)M_ * 128;                     // M*128 bf16
  unsigned short* hm1 = hm2 + (size_t)M_ * 128;                     // M*64 bf16
  unsigned short* dfeat_h = (unsigned short*)(ws + (size_t)M_ * 1280);  // M*256 bf16
  float* tail  = ws + (size_t)M_ * 1408;
  float* biasd = tail;                                // 1024
  float* bias0 = biasd + 1024;                        // 512
  float* bias1 = bias0 + 512;                         // 256
  float* bias2 = bias1 + 256;                         // 512
  unsigned int* wpk   = (unsigned int*)(bias2 + 512); // 1024*96
  unsigned int* wldsg = wpk + 1024 * 96;              // 32768
  unsigned int* wpk0  = wldsg + 32768;                // 512*64
  unsigned int* wpk1  = wpk0 + 512 * 64;              // 256*32
  unsigned int* wpk2  = wpk1 + 256 * 32;              // 512*64
  unsigned short* w0b = (unsigned short*)(wpk2 + 512 * 64);  // 512*320
  unsigned short* w1b = w0b + 512 * 320;                     // 256*128
  unsigned short* w2b = w1b + 256 * 128;                     // 512*512
  unsigned short* wdb = w2b + 512 * 512;                     // 1024*256
  unsigned short* fcw0b = wdb + 1024 * 256;                  // 128*128
  unsigned short* fcw1b = fcw0b + 128 * 128;                 // 64*64
  unsigned short* fcw2b = fcw1b + 64 * 64;                   // 128*128

  prep_kernel<<<256, 256, 0, stream>>>(w_ih_d, w_hh_d, b_ih_d, b_hh_d,
      b_ih0, b_hh0, b_ih1, b_hh1, b_ih2, b_hh2,
      w_hh0, w_hh1, w_hh2, w_ih0, w_ih1, w_ih2, fc_w0, fc_w1, fc_w2,
      dfeat_h, biasd, bias0, bias1, bias2, wpk, wldsg,
      wpk0, wpk1, wpk2, w0b, w1b, w2b, wdb, fcw0b, fcw1b, fcw2b);

  // input projections (bf16 MFMA)
  mfma_gemm<false><<<8 * 512, 256, 0, stream>>>(mod0, w0b, bias0, umask, gx0, 300, 320, 512);
  mfma_gemm<false><<<4 * 512, 256, 0, stream>>>(mod1, w1b, bias1, umask, gx1, 100, 128, 256);
  mfma_gemm<false><<<8 * 512, 256, 0, stream>>>(mod2, w2b, bias2, umask, gx2, 512, 512, 512);

  // fused modality scans (FC evicted; h -> hallm bf16)
  ModScanArgs a;
  a.gx0 = gx0; a.gx1 = gx1; a.gx2 = gx2;
  a.wk0 = wpk0; a.wk1 = wpk1; a.wk2 = wpk2;
  a.hm0 = hm0; a.hm1 = hm1; a.hm2 = hm2;
  mod_scan<<<768, 256, 0, stream>>>(a, nullptr);

  // FC heads (bf16 MFMA) -> dfeat
  fc_gemm<<<512 * 2, 256, 0, stream>>>(hm0, fcw0b, fc_b0, umask, dfeat_h, 128, 2, 100, 0);
  fc_gemm<<<512 * 1, 256, 0, stream>>>(hm1, fcw1b, fc_b1, umask, dfeat_h, 64, 1, 50, 100);
  fc_gemm<<<512 * 2, 256, 0, stream>>>(hm2, fcw2b, fc_b2, umask, dfeat_h, 128, 2, 100, 150);

  // dialogue input projection (bf16 MFMA, X already bf16)
  mfma_gemm<true><<<16 * 512, 256, 0, stream>>>(dfeat_h, wdb, biasd, nullptr, gxd, 256, 256, 1024);

  hipFuncSetAttribute(reinterpret_cast<const void*>(dlg_recur),
                      hipFuncAttributeMaxDynamicSharedMemorySize, DLG_LDS_BYTES);
  dlg_recur<<<256, 512, DLG_LDS_BYTES, stream>>>(gxd, wpk, wldsg, hall);

  out_head<<<M_ / 16, 256, 0, stream>>>(hall, fco_w, fco_b, sm_w, sm_b, (float*)d_out);
}

// Round 13
// 722.275 us; speedup vs baseline: 1.2868x; 1.2296x over previous
//
#include <hip/hip_runtime.h>

#define B_ 256
#define T_ 128
#define M_ (B_ * T_)
#define DH_ 256

__device__ __forceinline__ float sigf(float x) { return 1.0f / (1.0f + __expf(-x)); }
__device__ __forceinline__ float dot4(float4 a, float4 b) {
  return a.x * b.x + a.y * b.y + a.z * b.z + a.w * b.w;
}

typedef _Float16 half2v __attribute__((ext_vector_type(2)));
typedef short short8 __attribute__((ext_vector_type(8)));
typedef float f32x4 __attribute__((ext_vector_type(4)));

__device__ __forceinline__ float fdot2f(unsigned int w, unsigned int h, float acc) {
  half2v wv = __builtin_bit_cast(half2v, w);
  half2v hv = __builtin_bit_cast(half2v, h);
#if __has_builtin(__builtin_amdgcn_fdot2)
  return __builtin_amdgcn_fdot2(wv, hv, acc, false);
#else
  return acc + (float)wv[0] * (float)hv[0] + (float)wv[1] * (float)hv[1];
#endif
}
__device__ __forceinline__ unsigned int pk16(float a, float b) {
  unsigned short lo = __builtin_bit_cast(unsigned short, (_Float16)a);
  unsigned short hi = __builtin_bit_cast(unsigned short, (_Float16)b);
  return (unsigned int)lo | ((unsigned int)hi << 16);
}
__device__ __forceinline__ unsigned short bf16c(float x) {  // RNE f32->bf16
  unsigned int u = __builtin_bit_cast(unsigned int, x);
  return (unsigned short)((u + 0x7FFFu + ((u >> 16) & 1u)) >> 16);
}
__device__ __forceinline__ unsigned int bfpk(float a, float b) {
  return (unsigned int)bf16c(a) | ((unsigned int)bf16c(b) << 16);
}

// ---------------------------------------------------------------------------
// prep: combined biases; bf16 zero-padded GEMM weights (input projections,
// dialogue projection, per-modality FC); fp16-packed recurrent weights
// (dialogue reg/LDS split + modality register rows). Round-8 exact.
// ---------------------------------------------------------------------------
__global__ void prep_kernel(const float* __restrict__ w_ih_d, const float* __restrict__ w_hh_d,
                            const float* __restrict__ b_ih_d, const float* __restrict__ b_hh_d,
                            const float* __restrict__ b_ih0, const float* __restrict__ b_hh0,
                            const float* __restrict__ b_ih1, const float* __restrict__ b_hh1,
                            const float* __restrict__ b_ih2, const float* __restrict__ b_hh2,
                            const float* __restrict__ w_hh0, const float* __restrict__ w_hh1,
                            const float* __restrict__ w_hh2,
                            const float* __restrict__ w_ih0, const float* __restrict__ w_ih1,
                            const float* __restrict__ w_ih2,
                            const float* __restrict__ fc_w0, const float* __restrict__ fc_w1,
                            const float* __restrict__ fc_w2,
                            unsigned short* __restrict__ dfeat_h,
                            float* __restrict__ biasd, float* __restrict__ bias0,
                            float* __restrict__ bias1, float* __restrict__ bias2,
                            unsigned int* __restrict__ wpk, unsigned int* __restrict__ wldsg,
                            unsigned int* __restrict__ wpk0, unsigned int* __restrict__ wpk1,
                            unsigned int* __restrict__ wpk2,
                            unsigned short* __restrict__ w0b, unsigned short* __restrict__ w1b,
                            unsigned short* __restrict__ w2b, unsigned short* __restrict__ wdb,
                            unsigned short* __restrict__ fcw0b, unsigned short* __restrict__ fcw1b,
                            unsigned short* __restrict__ fcw2b) {
  int idx = blockIdx.x * blockDim.x + threadIdx.x;
  int stride = gridDim.x * blockDim.x;
  for (int i = idx; i < 512 * 320; i += stride) {
    int r = i / 320, k = i % 320;
    w0b[i] = (k < 300) ? bf16c(w_ih0[(size_t)r * 300 + k]) : (unsigned short)0;
  }
  for (int i = idx; i < 256 * 128; i += stride) {
    int r = i >> 7, k = i & 127;
    w1b[i] = (k < 100) ? bf16c(w_ih1[(size_t)r * 100 + k]) : (unsigned short)0;
  }
  for (int i = idx; i < 512 * 512; i += stride) w2b[i] = bf16c(w_ih2[i]);
  for (int i = idx; i < 1024 * 256; i += stride) {
    int r = i >> 8, k = i & 255;
    wdb[i] = (k < 250) ? bf16c(w_ih_d[(size_t)r * 250 + k]) : (unsigned short)0;
  }
  for (int i = idx; i < 128 * 128; i += stride) {
    int f = i >> 7, k = i & 127;
    fcw0b[i] = (f < 100) ? bf16c(fc_w0[(size_t)f * 128 + k]) : (unsigned short)0;
    fcw2b[i] = (f < 100) ? bf16c(fc_w2[(size_t)f * 128 + k]) : (unsigned short)0;
  }
  for (int i = idx; i < 64 * 64; i += stride) {
    int f = i >> 6, k = i & 63;
    fcw1b[i] = (f < 50) ? bf16c(fc_w1[(size_t)f * 64 + k]) : (unsigned short)0;
  }
  for (int i = idx; i < M_ * 6; i += stride)   // zero dfeat_h pad cols 250..255
    dfeat_h[(size_t)(i / 6) * 256 + 250 + (i % 6)] = 0;
  for (int i = idx; i < 1024 * 96; i += stride) {
    int r = i / 96, k0 = (i % 96) * 2;
    wpk[i] = pk16(w_hh_d[(size_t)r * 256 + k0], w_hh_d[(size_t)r * 256 + k0 + 1]);
  }
  for (int i = idx; i < 32768; i += stride) {
    int jj = i >> 12, rem = i & 4095, r = rem >> 2, q = rem & 3;
    int p = 96 + 4 * jj + q;
    wldsg[i] = pk16(w_hh_d[(size_t)r * 256 + 2 * p], w_hh_d[(size_t)r * 256 + 2 * p + 1]);
  }
  for (int i = idx; i < 512 * 64; i += stride) {
    int r = i >> 6, p = (i & 63) * 2;
    wpk0[i] = pk16(w_hh0[(size_t)r * 128 + p], w_hh0[(size_t)r * 128 + p + 1]);
    wpk2[i] = pk16(w_hh2[(size_t)r * 128 + p], w_hh2[(size_t)r * 128 + p + 1]);
  }
  for (int i = idx; i < 256 * 32; i += stride) {
    int r = i >> 5, p = (i & 31) * 2;
    wpk1[i] = pk16(w_hh1[(size_t)r * 64 + p], w_hh1[(size_t)r * 64 + p + 1]);
  }
  for (int i = idx; i < 1024; i += stride) biasd[i] = b_ih_d[i] + b_hh_d[i];
  for (int i = idx; i < 512; i += stride) bias0[i] = b_ih0[i] + b_hh0[i];
  for (int i = idx; i < 256; i += stride) bias1[i] = b_ih1[i] + b_hh1[i];
  for (int i = idx; i < 512; i += stride) bias2[i] = b_ih2[i] + b_hh2[i];
}

// ---------------------------------------------------------------------------
// proj_all: the 3 input-projection GEMMs merged into ONE launch (blockIdx
// range dispatch) — removes 2 launch serializations and packs the machine
// (mod1's 2048 blocks no longer run alone). Body = verified mfma_gemm<false>.
// Grid: [0,4096) mod0 | [4096,6144) mod1 | [6144,10240) mod2.
// ---------------------------------------------------------------------------
struct ProjArgs {
  const float* x0; const float* x1; const float* x2;
  const unsigned short* w0; const unsigned short* w1; const unsigned short* w2;
  const float* b0; const float* b1; const float* b2;
  float* c0; float* c1; float* c2;
};

__global__ __launch_bounds__(256) void proj_all(ProjArgs pa,
    const float* __restrict__ umask) {
  __shared__ __align__(16) unsigned short Xs[64][40];
  __shared__ __align__(16) unsigned short Ws[64][40];
  const int tid = threadIdx.x;
  const int dg = blockIdx.x;
  const float* X; const unsigned short* Wb; const float* bias; float* C;
  int K, Kp, N, d;
  if (dg < 4096)      { X = pa.x0; Wb = pa.w0; bias = pa.b0; C = pa.c0; K = 300; Kp = 320; N = 512; d = dg; }
  else if (dg < 6144) { X = pa.x1; Wb = pa.w1; bias = pa.b1; C = pa.c1; K = 100; Kp = 128; N = 256; d = dg - 4096; }
  else                { X = pa.x2; Wb = pa.w2; bias = pa.b2; C = pa.c2; K = 512; Kp = 512; N = 512; d = dg - 6144; }
  const int nx = N >> 6;
  const int n0 = ((d % (nx << 3)) >> 3) << 6;
  const int m0 = (((d / (nx << 3)) << 3) + (d & 7)) << 6;
  const int srow = tid >> 2, kq = tid & 3;
  const int w = tid >> 6, lane = tid & 63;
  const int lr = lane & 15, lk = lane >> 4;
  const int t = m0 >> 8, b0 = m0 & 255;
  const float* Xf = X + ((size_t)(b0 + srow) * T_ + t) * K;
  const unsigned short* Wr = Wb + (size_t)(n0 + srow) * Kp;
  f32x4 acc[4];
#pragma unroll
  for (int j = 0; j < 4; j++) acc[j] = (f32x4){0.f, 0.f, 0.f, 0.f};

  for (int k0 = 0; k0 < Kp; k0 += 32) {
    const int kk = k0 + kq * 8;
    float4 va = (kk + 3 < K) ? *reinterpret_cast<const float4*>(Xf + kk)
                             : make_float4(0.f, 0.f, 0.f, 0.f);
    float4 vb = (kk + 7 < K) ? *reinterpret_cast<const float4*>(Xf + kk + 4)
                             : make_float4(0.f, 0.f, 0.f, 0.f);
    uint4 xa;
    xa.x = bfpk(va.x, va.y); xa.y = bfpk(va.z, va.w);
    xa.z = bfpk(vb.x, vb.y); xa.w = bfpk(vb.z, vb.w);
    uint4 wv = *reinterpret_cast<const uint4*>(Wr + kk);
    __syncthreads();
    *reinterpret_cast<uint4*>(&Xs[srow][kq * 8]) = xa;
    *reinterpret_cast<uint4*>(&Ws[srow][kq * 8]) = wv;
    __syncthreads();
    short8 af = *reinterpret_cast<const short8*>(&Xs[w * 16 + lr][lk * 8]);
#pragma unroll
    for (int j = 0; j < 4; j++) {
      short8 bf = *reinterpret_cast<const short8*>(&Ws[j * 16 + lr][lk * 8]);
      acc[j] = __builtin_amdgcn_mfma_f32_16x16x32_bf16(af, bf, acc[j], 0, 0, 0);
    }
  }
#pragma unroll
  for (int j = 0; j < 4; j++) {
    const int col = n0 + j * 16 + lr;
    const float bv = bias[col];
#pragma unroll
    for (int r = 0; r < 4; r++) {
      const int mrow = m0 + w * 16 + lk * 4 + r;
      float um = umask[(b0 + w * 16 + lk * 4 + r) * T_ + t];
      C[(size_t)mrow * N + col] = acc[j][r] * um + bv;
    }
  }
}

// ---------------------------------------------------------------------------
// mfma_gemm<true>: dialogue input projection (X already bf16). Verified.
// ---------------------------------------------------------------------------
__global__ __launch_bounds__(256) void gxd_gemm(
    const unsigned short* __restrict__ Xh, const unsigned short* __restrict__ Wb,
    const float* __restrict__ bias, float* __restrict__ C, int Kp, int N) {
  __shared__ __align__(16) unsigned short Xs[64][40];
  __shared__ __align__(16) unsigned short Ws[64][40];
  const int tid = threadIdx.x;
  const int d = blockIdx.x;
  const int nx = N >> 6;
  const int n0 = ((d % (nx << 3)) >> 3) << 6;
  const int m0 = (((d / (nx << 3)) << 3) + (d & 7)) << 6;
  const int srow = tid >> 2, kq = tid & 3;
  const int w = tid >> 6, lane = tid & 63;
  const int lr = lane & 15, lk = lane >> 4;
  const unsigned short* Xp = Xh + (size_t)(m0 + srow) * Kp;
  const unsigned short* Wr = Wb + (size_t)(n0 + srow) * Kp;
  f32x4 acc[4];
#pragma unroll
  for (int j = 0; j < 4; j++) acc[j] = (f32x4){0.f, 0.f, 0.f, 0.f};
  for (int k0 = 0; k0 < Kp; k0 += 32) {
    const int kk = k0 + kq * 8;
    uint4 xa = *reinterpret_cast<const uint4*>(Xp + kk);
    uint4 wv = *reinterpret_cast<const uint4*>(Wr + kk);
    __syncthreads();
    *reinterpret_cast<uint4*>(&Xs[srow][kq * 8]) = xa;
    *reinterpret_cast<uint4*>(&Ws[srow][kq * 8]) = wv;
    __syncthreads();
    short8 af = *reinterpret_cast<const short8*>(&Xs[w * 16 + lr][lk * 8]);
#pragma unroll
    for (int j = 0; j < 4; j++) {
      short8 bf = *reinterpret_cast<const short8*>(&Ws[j * 16 + lr][lk * 8]);
      acc[j] = __builtin_amdgcn_mfma_f32_16x16x32_bf16(af, bf, acc[j], 0, 0, 0);
    }
  }
#pragma unroll
  for (int j = 0; j < 4; j++) {
    const int col = n0 + j * 16 + lr;
    const float bv = bias[col];
#pragma unroll
    for (int r = 0; r < 4; r++) {
      const int mrow = m0 + w * 16 + lk * 4 + r;
      C[(size_t)mrow * N + col] = acc[j][r] + bv;
    }
  }
}

// ---------------------------------------------------------------------------
// fc_all: the 3 per-modality FC-head GEMMs merged into one launch.
// Grid: [0,1024) mod0 | [1024,1536) mod1 | [1536,2560) mod2.
// ---------------------------------------------------------------------------
struct FcArgs {
  const unsigned short* x0; const unsigned short* x1; const unsigned short* x2;
  const unsigned short* w0; const unsigned short* w1; const unsigned short* w2;
  const float* b0; const float* b1; const float* b2;
};

__global__ __launch_bounds__(256) void fc_all(FcArgs fa,
    const float* __restrict__ umask, unsigned short* __restrict__ dfeat_h) {
  __shared__ __align__(16) unsigned short Xs[64][40];
  __shared__ __align__(16) unsigned short Ws[64][40];
  const int tid = threadIdx.x;
  const int dg = blockIdx.x;
  const unsigned short* Xh; const unsigned short* Wb; const float* fcb;
  int Kp, nx, F, col0, d;
  if (dg < 1024)      { Xh = fa.x0; Wb = fa.w0; fcb = fa.b0; Kp = 128; nx = 2; F = 100; col0 = 0;   d = dg; }
  else if (dg < 1536) { Xh = fa.x1; Wb = fa.w1; fcb = fa.b1; Kp = 64;  nx = 1; F = 50;  col0 = 100; d = dg - 1024; }
  else                { Xh = fa.x2; Wb = fa.w2; fcb = fa.b2; Kp = 128; nx = 2; F = 100; col0 = 150; d = dg - 1536; }
  const int n0 = (d % nx) * 64;
  const int m0 = (d / nx) * 64;
  const int srow = tid >> 2, kq = tid & 3;
  const int w = tid >> 6, lane = tid & 63;
  const int lr = lane & 15, lk = lane >> 4;
  const unsigned short* Xp = Xh + (size_t)(m0 + srow) * Kp;
  const unsigned short* Wr = Wb + (size_t)(n0 + srow) * Kp;
  f32x4 acc[4];
#pragma unroll
  for (int j = 0; j < 4; j++) acc[j] = (f32x4){0.f, 0.f, 0.f, 0.f};
  for (int k0 = 0; k0 < Kp; k0 += 32) {
    const int kk = k0 + kq * 8;
    uint4 xa = *reinterpret_cast<const uint4*>(Xp + kk);
    uint4 wv = *reinterpret_cast<const uint4*>(Wr + kk);
    __syncthreads();
    *reinterpret_cast<uint4*>(&Xs[srow][kq * 8]) = xa;
    *reinterpret_cast<uint4*>(&Ws[srow][kq * 8]) = wv;
    __syncthreads();
    short8 af = *reinterpret_cast<const short8*>(&Xs[w * 16 + lr][lk * 8]);
#pragma unroll
    for (int j = 0; j < 4; j++) {
      short8 bf = *reinterpret_cast<const short8*>(&Ws[j * 16 + lr][lk * 8]);
      acc[j] = __builtin_amdgcn_mfma_f32_16x16x32_bf16(af, bf, acc[j], 0, 0, 0);
    }
  }
#pragma unroll
  for (int j = 0; j < 4; j++) {
    const int coln = n0 + j * 16 + lr;
    const float bv = (coln < F) ? fcb[coln] : 0.f;
#pragma unroll
    for (int r = 0; r < 4; r++) {
      const int mrow = m0 + w * 16 + lk * 4 + r;
      if (coln < F) {
        const int t = mrow >> 8, b = mrow & 255;
        float um = umask[b * T_ + t];
        dfeat_h[(size_t)mrow * 256 + col0 + coln] = bf16c(tanhf(acc[j][r] + bv) * um);
      }
    }
  }
}

// ---------------------------------------------------------------------------
// mod_scan: round-8 exact (measured good): waves_per_eu(2,3), no pins.
// ---------------------------------------------------------------------------
struct ModScanArgs {
  const float* gx0; const float* gx1; const float* gx2;
  const unsigned int* wk0; const unsigned int* wk1; const unsigned int* wk2;
  unsigned short* hm0; unsigned short* hm1; unsigned short* hm2;
};

__device__ __forceinline__ void mod_body128s(
    const float* __restrict__ gx, const unsigned int* __restrict__ wk,
    int b, unsigned short* __restrict__ hallm, unsigned int* smem) {
  float* gbuf = (float*)smem;          // 512 f32
  unsigned int* hbuf = smem + 512;     // 64 u32
  const int tid = threadIdx.x;
  uint4 wrA[16], wrB[16];
  {
    const uint4* wpA = reinterpret_cast<const uint4*>(wk + (size_t)tid * 64);
    const uint4* wpB = reinterpret_cast<const uint4*>(wk + (size_t)(tid + 256) * 64);
#pragma unroll
    for (int j = 0; j < 16; j++) { wrA[j] = wpA[j]; wrB[j] = wpB[j]; }
  }
  if (tid < 64) hbuf[tid] = 0u;
  float creg = 0.f;
  __syncthreads();
  const uint4* h4 = reinterpret_cast<const uint4*>(hbuf);
  const float* gp = gx + (size_t)b * 512 + tid;
  float gcA = gp[0], gcB = gp[256];
  for (int t = 0; t < T_; t++) {
    float gnA = 0.f, gnB = 0.f;
    if (t + 1 < T_) {
      gnA = gp[(size_t)(t + 1) * B_ * 512];
      gnB = gp[(size_t)(t + 1) * B_ * 512 + 256];
    }
    float a0 = 0.f, a1 = 0.f, a2 = 0.f, a3 = 0.f;
    float d0 = 0.f, d1 = 0.f, d2 = 0.f, d3 = 0.f;
#pragma unroll
    for (int j = 0; j < 16; j++) {
      uint4 hv = h4[j];
      a0 = fdot2f(wrA[j].x, hv.x, a0);
      a1 = fdot2f(wrA[j].y, hv.y, a1);
      a2 = fdot2f(wrA[j].z, hv.z, a2);
      a3 = fdot2f(wrA[j].w, hv.w, a3);
      d0 = fdot2f(wrB[j].x, hv.x, d0);
      d1 = fdot2f(wrB[j].y, hv.y, d1);
      d2 = fdot2f(wrB[j].z, hv.z, d2);
      d3 = fdot2f(wrB[j].w, hv.w, d3);
    }
    gbuf[tid] = (a0 + a1) + (a2 + a3) + gcA;      // gx includes bias + umask'd x
    gbuf[tid + 256] = (d0 + d1) + (d2 + d3) + gcB;
    gcA = gnA; gcB = gnB;
    __syncthreads();                               // S1: gates ready
    if (tid < 128) {
      float i_ = sigf(gbuf[tid]);
      float f_ = sigf(gbuf[128 + tid]);
      float g_ = tanhf(gbuf[256 + tid]);
      float o_ = sigf(gbuf[384 + tid]);
      float cc = f_ * creg + i_ * g_;
      creg = cc;
      float h2 = tanhf(o_ * tanhf(cc));            // extra tanh on hidden state
      hallm[((size_t)t * B_ + b) * 128 + tid] = bf16c(h2);
      float hp = __shfl_xor(h2, 1);
      if ((tid & 1) == 0) hbuf[tid >> 1] = pk16(h2, hp);
    }
    __syncthreads();                               // S2: h_t staged
  }
}

__device__ __forceinline__ void mod_body64s(
    const float* __restrict__ gx, const unsigned int* __restrict__ wk,
    int b, unsigned short* __restrict__ hallm, unsigned int* smem) {
  float* gbuf = (float*)smem;          // 256 f32
  unsigned int* hbuf = smem + 512;     // 32 u32
  const int tid = threadIdx.x;
  uint4 wr[8];
  {
    const uint4* wp = reinterpret_cast<const uint4*>(wk + (size_t)tid * 32);
#pragma unroll
    for (int j = 0; j < 8; j++) wr[j] = wp[j];
  }
  if (tid < 32) hbuf[tid] = 0u;
  float creg = 0.f;
  __syncthreads();
  const uint4* h4 = reinterpret_cast<const uint4*>(hbuf);
  const float* gp = gx + (size_t)b * 256 + tid;
  float gc = gp[0];
  for (int t = 0; t < T_; t++) {
    float gn = (t + 1 < T_) ? gp[(size_t)(t + 1) * B_ * 256] : 0.f;
    float a0 = 0.f, a1 = 0.f, a2 = 0.f, a3 = 0.f;
#pragma unroll
    for (int j = 0; j < 8; j++) {
      uint4 hv = h4[j];
      a0 = fdot2f(wr[j].x, hv.x, a0);
      a1 = fdot2f(wr[j].y, hv.y, a1);
      a2 = fdot2f(wr[j].z, hv.z, a2);
      a3 = fdot2f(wr[j].w, hv.w, a3);
    }
    gbuf[tid] = (a0 + a1) + (a2 + a3) + gc;
    gc = gn;
    __syncthreads();                               // S1
    if (tid < 64) {
      float i_ = sigf(gbuf[tid]);
      float f_ = sigf(gbuf[64 + tid]);
      float g_ = tanhf(gbuf[128 + tid]);
      float o_ = sigf(gbuf[192 + tid]);
      float cc = f_ * creg + i_ * g_;
      creg = cc;
      float h2 = tanhf(o_ * tanhf(cc));
      hallm[((size_t)t * B_ + b) * 64 + tid] = bf16c(h2);
      float hp = __shfl_xor(h2, 1);
      if ((tid & 1) == 0) hbuf[tid >> 1] = pk16(h2, hp);
    }
    __syncthreads();                               // S2
  }
}

__global__ __launch_bounds__(256)
__attribute__((amdgpu_waves_per_eu(2, 3)))
void mod_scan(ModScanArgs a, unsigned short* __restrict__ hm_unused) {
  __shared__ __align__(16) unsigned int smem[576];   // gbuf(512) | hbuf(64)
  const int blk = blockIdx.x;
  if (blk < 512) {
    const int mi = blk >> 8, b = blk & 255;
    mod_body128s(mi ? a.gx2 : a.gx0, mi ? a.wk2 : a.wk0, b,
                 mi ? a.hm2 : a.hm0, smem);
  } else {
    mod_body64s(a.gx1, a.wk1, blk - 512, a.hm1, smem);
  }
}

// ---------------------------------------------------------------------------
// dlg_recur: round-8 exact (best measured: 283 µs). Rounds 9-12 established:
// (1) the allocator will not hold >128 arch VGPRs for this shape — attrs,
// pins, AGPR staging all fail or regress; (2) the kernel's primary cost is
// the DS pipe (384 b128-class ops/step = ~1.9 µs/step), which the L2 weight
// re-reads largely hide under. This is its structural point for this design.
// ---------------------------------------------------------------------------
#define DLG_LDS_BYTES (131072 + 4096 + 512)

__global__ __launch_bounds__(512, 2) void dlg_recur(
    const float* __restrict__ gxd, const unsigned int* __restrict__ wpk,
    const unsigned int* __restrict__ wldsg, float* __restrict__ hall) {
  extern __shared__ char smem[];
  unsigned int* wl = (unsigned int*)smem;                       // [8][1024][4]
  float* gbuf = (float*)(smem + 131072);                        // [1024]
  _Float16* hbuf_h = (_Float16*)(smem + 131072 + 4096);         // [256]
  const uint4* hbuf4 = (const uint4*)hbuf_h;                    // [32]
  const uint4* wl4 = (const uint4*)wl;
  const int tid = threadIdx.x;
  const int b = blockIdx.x;

  for (int i = tid; i < 32768; i += 512) wl[i] = wldsg[i];
  unsigned int wr0[96], wr1[96];
  {
    const uint4* p0 = reinterpret_cast<const uint4*>(wpk + (size_t)tid * 96);
    const uint4* p1 = reinterpret_cast<const uint4*>(wpk + (size_t)(tid + 512) * 96);
#pragma unroll
    for (int j = 0; j < 24; j++) {
      uint4 v0 = p0[j], v1 = p1[j];
      wr0[4 * j + 0] = v0.x; wr0[4 * j + 1] = v0.y; wr0[4 * j + 2] = v0.z; wr0[4 * j + 3] = v0.w;
      wr1[4 * j + 0] = v1.x; wr1[4 * j + 1] = v1.y; wr1[4 * j + 2] = v1.z; wr1[4 * j + 3] = v1.w;
    }
  }
  if (tid < 32) reinterpret_cast<uint4*>(const_cast<_Float16*>(hbuf_h))[tid] = uint4{0, 0, 0, 0};
  float creg = 0.f;
  __syncthreads();

  const float* gbase = gxd + (size_t)b * 1024 + tid;
  float gc0 = gbase[0], gc1 = gbase[512];
  for (int t = 0; t < T_; t++) {
    float gn0 = 0.f, gn1 = 0.f;
    if (t + 1 < T_) {
      gn0 = gbase[(size_t)(t + 1) * B_ * 1024];
      gn1 = gbase[(size_t)(t + 1) * B_ * 1024 + 512];
    }
    float a0 = 0.f, a1 = 0.f;
#pragma unroll
    for (int j = 0; j < 24; j++) {          // pairs 0..95 (registers)
      uint4 hv = hbuf4[j];
      a0 = fdot2f(wr0[4 * j + 0], hv.x, a0); a1 = fdot2f(wr1[4 * j + 0], hv.x, a1);
      a0 = fdot2f(wr0[4 * j + 1], hv.y, a0); a1 = fdot2f(wr1[4 * j + 1], hv.y, a1);
      a0 = fdot2f(wr0[4 * j + 2], hv.z, a0); a1 = fdot2f(wr1[4 * j + 2], hv.z, a1);
      a0 = fdot2f(wr0[4 * j + 3], hv.w, a0); a1 = fdot2f(wr1[4 * j + 3], hv.w, a1);
    }
#pragma unroll
    for (int jj = 0; jj < 8; jj++) {        // pairs 96..127 (LDS, b128)
      uint4 hv = hbuf4[24 + jj];
      uint4 wa = wl4[jj * 1024 + tid];
      uint4 wc = wl4[jj * 1024 + tid + 512];
      a0 = fdot2f(wa.x, hv.x, a0); a1 = fdot2f(wc.x, hv.x, a1);
      a0 = fdot2f(wa.y, hv.y, a0); a1 = fdot2f(wc.y, hv.y, a1);
      a0 = fdot2f(wa.z, hv.z, a0); a1 = fdot2f(wc.z, hv.z, a1);
      a0 = fdot2f(wa.w, hv.w, a0); a1 = fdot2f(wc.w, hv.w, a1);
    }
    gbuf[tid] = a0 + gc0;
    gbuf[tid + 512] = a1 + gc1;
    __syncthreads();
    if (tid < DH_) {
      float i_ = sigf(gbuf[tid]);
      float f_ = sigf(gbuf[DH_ + tid]);
      float g_ = tanhf(gbuf[2 * DH_ + tid]);
      float o_ = sigf(gbuf[3 * DH_ + tid]);
      float c2 = f_ * creg + i_ * g_;
      creg = c2;
      float h2 = o_ * tanhf(c2);
      hall[((size_t)t * B_ + b) * DH_ + tid] = h2;
      hbuf_h[tid] = (_Float16)h2;
    }
    gc0 = gn0; gc1 = gn1;
    __syncthreads();
  }
}

// ---------------------------------------------------------------------------
// out_head: fc_out + tanh + smax + log_softmax (unchanged).
// ---------------------------------------------------------------------------
__global__ __launch_bounds__(256) void out_head(
    const float* __restrict__ hall, const float* __restrict__ fcow,
    const float* __restrict__ fcob, const float* __restrict__ smw,
    const float* __restrict__ smb, float* __restrict__ out) {
  __shared__ __align__(16) float h_lds[16][260];
  __shared__ __align__(16) float fco[16][132];
  __shared__ float lg[16][6];
  const int tid = threadIdx.x;
  const int m0 = blockIdx.x * 16;
  {
    const float* src = hall + (size_t)m0 * DH_;
    for (int e = tid; e < 1024; e += 256) {
      float4 v = reinterpret_cast<const float4*>(src)[e];
      const int r = e >> 6, k = (e & 63) * 4;
      *reinterpret_cast<float4*>(&h_lds[r][k]) = v;
    }
  }
  __syncthreads();
  {
    const int f = tid & 127, half = tid >> 7;
    float acc[8];
    const float fb = fcob[f];
#pragma unroll
    for (int r = 0; r < 8; r++) acc[r] = fb;
    const float* wrow = fcow + (size_t)f * DH_;
    for (int k = 0; k < DH_; k += 4) {
      float4 w4 = *reinterpret_cast<const float4*>(wrow + k);
#pragma unroll
      for (int r = 0; r < 8; r++)
        acc[r] += dot4(w4, *reinterpret_cast<const float4*>(&h_lds[half * 8 + r][k]));
    }
#pragma unroll
    for (int r = 0; r < 8; r++) fco[half * 8 + r][f] = tanhf(acc[r]);
  }
  __syncthreads();
  if (tid < 96) {
    const int r = tid / 6, cc = tid % 6;
    float a = smb[cc];
    const float* sw = smw + cc * 128;
#pragma unroll 4
    for (int k = 0; k < 128; k++) a += sw[k] * fco[r][k];
    lg[r][cc] = a;
  }
  __syncthreads();
  if (tid < 16) {
    const int m = m0 + tid;
    const int t = m >> 8, b = m & 255;
    float mx = lg[tid][0];
#pragma unroll
    for (int cc = 1; cc < 6; cc++) mx = fmaxf(mx, lg[tid][cc]);
    float ssum = 0.f;
#pragma unroll
    for (int cc = 0; cc < 6; cc++) ssum += __expf(lg[tid][cc] - mx);
    float lse = mx + logf(ssum);
#pragma unroll
    for (int cc = 0; cc < 6; cc++)
      out[((size_t)b * T_ + t) * 6 + cc] = lg[tid][cc] - lse;
  }
}

// ---------------------------------------------------------------------------
extern "C" void kernel_launch(void* const* d_in, const int* in_sizes, int n_in,
                              void* d_out, int out_size, void* d_ws, size_t ws_size,
                              hipStream_t stream) {
  const float* mod0  = (const float*)d_in[0];
  const float* mod1  = (const float*)d_in[1];
  const float* mod2  = (const float*)d_in[2];
  const float* umask = (const float*)d_in[3];
  const float* w_ih0 = (const float*)d_in[4];
  const float* w_hh0 = (const float*)d_in[5];
  const float* b_ih0 = (const float*)d_in[6];
  const float* b_hh0 = (const float*)d_in[7];
  const float* fc_w0 = (const float*)d_in[8];
  const float* fc_b0 = (const float*)d_in[9];
  const float* w_ih1 = (const float*)d_in[10];
  const float* w_hh1 = (const float*)d_in[11];
  const float* b_ih1 = (const float*)d_in[12];
  const float* b_hh1 = (const float*)d_in[13];
  const float* fc_w1 = (const float*)d_in[14];
  const float* fc_b1 = (const float*)d_in[15];
  const float* w_ih2 = (const float*)d_in[16];
  const float* w_hh2 = (const float*)d_in[17];
  const float* b_ih2 = (const float*)d_in[18];
  const float* b_hh2 = (const float*)d_in[19];
  const float* fc_w2 = (const float*)d_in[20];
  const float* fc_b2 = (const float*)d_in[21];
  const float* w_ih_d = (const float*)d_in[22];
  const float* w_hh_d = (const float*)d_in[23];
  const float* b_ih_d = (const float*)d_in[24];
  const float* b_hh_d = (const float*)d_in[25];
  const float* fco_w  = (const float*)d_in[26];
  const float* fco_b  = (const float*)d_in[27];
  const float* sm_w   = (const float*)d_in[28];
  const float* sm_b   = (const float*)d_in[29];

  // workspace layout (float units):
  //   [0, M*1280): gx0|gx1|gx2 -> reused as gxd [0,M*1024)
  //   [M*1024, M*1280): hallm0|hallm2|hallm1 (bf16) -> later hall (fp32)
  float* ws    = (float*)d_ws;
  float* gx0   = ws;                                  // M*512
  float* gx1   = gx0 + (size_t)M_ * 512;              // M*256
  float* gx2   = gx1 + (size_t)M_ * 256;              // M*512
  float* gxd   = ws;                                  // M*1024 (reuse)
  float* hall  = ws + (size_t)M_ * 1024;              // M*256 fp32
  unsigned short* hm0 = (unsigned short*)(ws + (size_t)M_ * 1024);  // M*128 bf16
  unsigned short* hm2 = hm0 + (size_t)M_ * 128;                     // M*128 bf16
  unsigned short* hm1 = hm2 + (size_t)M_ * 128;                     // M*64 bf16
  unsigned short* dfeat_h = (unsigned short*)(ws + (size_t)M_ * 1280);  // M*256 bf16
  float* tail  = ws + (size_t)M_ * 1408;
  float* biasd = tail;                                // 1024
  float* bias0 = biasd + 1024;                        // 512
  float* bias1 = bias0 + 512;                         // 256
  float* bias2 = bias1 + 256;                         // 512
  unsigned int* wpk   = (unsigned int*)(bias2 + 512); // 1024*96
  unsigned int* wldsg = wpk + 1024 * 96;              // 32768
  unsigned int* wpk0  = wldsg + 32768;                // 512*64
  unsigned int* wpk1  = wpk0 + 512 * 64;              // 256*32
  unsigned int* wpk2  = wpk1 + 256 * 32;              // 512*64
  unsigned short* w0b = (unsigned short*)(wpk2 + 512 * 64);  // 512*320
  unsigned short* w1b = w0b + 512 * 320;                     // 256*128
  unsigned short* w2b = w1b + 256 * 128;                     // 512*512
  unsigned short* wdb = w2b + 512 * 512;                     // 1024*256
  unsigned short* fcw0b = wdb + 1024 * 256;                  // 128*128
  unsigned short* fcw1b = fcw0b + 128 * 128;                 // 64*64
  unsigned short* fcw2b = fcw1b + 64 * 64;                   // 128*128

  prep_kernel<<<256, 256, 0, stream>>>(w_ih_d, w_hh_d, b_ih_d, b_hh_d,
      b_ih0, b_hh0, b_ih1, b_hh1, b_ih2, b_hh2,
      w_hh0, w_hh1, w_hh2, w_ih0, w_ih1, w_ih2, fc_w0, fc_w1, fc_w2,
      dfeat_h, biasd, bias0, bias1, bias2, wpk, wldsg,
      wpk0, wpk1, wpk2, w0b, w1b, w2b, wdb, fcw0b, fcw1b, fcw2b);

  // input projections (bf16 MFMA), merged into one launch
  ProjArgs pa;
  pa.x0 = mod0; pa.x1 = mod1; pa.x2 = mod2;
  pa.w0 = w0b;  pa.w1 = w1b;  pa.w2 = w2b;
  pa.b0 = bias0; pa.b1 = bias1; pa.b2 = bias2;
  pa.c0 = gx0;  pa.c1 = gx1;  pa.c2 = gx2;
  proj_all<<<10240, 256, 0, stream>>>(pa, umask);

  // fused modality scans (FC evicted; h -> hallm bf16)
  ModScanArgs a;
  a.gx0 = gx0; a.gx1 = gx1; a.gx2 = gx2;
  a.wk0 = wpk0; a.wk1 = wpk1; a.wk2 = wpk2;
  a.hm0 = hm0; a.hm1 = hm1; a.hm2 = hm2;
  mod_scan<<<768, 256, 0, stream>>>(a, nullptr);

  // FC heads (bf16 MFMA) -> dfeat, merged into one launch
  FcArgs fa;
  fa.x0 = hm0; fa.x1 = hm1; fa.x2 = hm2;
  fa.w0 = fcw0b; fa.w1 = fcw1b; fa.w2 = fcw2b;
  fa.b0 = fc_b0; fa.b1 = fc_b1; fa.b2 = fc_b2;
  fc_all<<<2560, 256, 0, stream>>>(fa, umask, dfeat_h);

  // dialogue input projection (bf16 MFMA, X already bf16)
  gxd_gemm<<<16 * 512, 256, 0, stream>>>(dfeat_h, wdb, biasd, gxd, 256, 1024);

  hipFuncSetAttribute(reinterpret_cast<const void*>(dlg_recur),
                      hipFuncAttributeMaxDynamicSharedMemorySize, DLG_LDS_BYTES);
  dlg_recur<<<256, 512, DLG_LDS_BYTES, stream>>>(gxd, wpk, wldsg, hall);

  out_head<<<M_ / 16, 256, 0, stream>>>(hall, fco_w, fco_b, sm_w, sm_b, (float*)d_out);
}

// Round 14
// 688.365 us; speedup vs baseline: 1.3502x; 1.0493x over previous
//
#include <hip/hip_runtime.h>

#define B_ 256
#define T_ 128
#define M_ (B_ * T_)
#define DH_ 256

__device__ __forceinline__ float sigf(float x) { return 1.0f / (1.0f + __expf(-x)); }
__device__ __forceinline__ float dot4(float4 a, float4 b) {
  return a.x * b.x + a.y * b.y + a.z * b.z + a.w * b.w;
}

typedef _Float16 half2v __attribute__((ext_vector_type(2)));
typedef short short8 __attribute__((ext_vector_type(8)));
typedef float f32x4 __attribute__((ext_vector_type(4)));

__device__ __forceinline__ float fdot2f(unsigned int w, unsigned int h, float acc) {
  half2v wv = __builtin_bit_cast(half2v, w);
  half2v hv = __builtin_bit_cast(half2v, h);
#if __has_builtin(__builtin_amdgcn_fdot2)
  return __builtin_amdgcn_fdot2(wv, hv, acc, false);
#else
  return acc + (float)wv[0] * (float)hv[0] + (float)wv[1] * (float)hv[1];
#endif
}
__device__ __forceinline__ unsigned int pk16(float a, float b) {
  unsigned short lo = __builtin_bit_cast(unsigned short, (_Float16)a);
  unsigned short hi = __builtin_bit_cast(unsigned short, (_Float16)b);
  return (unsigned int)lo | ((unsigned int)hi << 16);
}
__device__ __forceinline__ unsigned short bf16c(float x) {  // RNE f32->bf16
  unsigned int u = __builtin_bit_cast(unsigned int, x);
  return (unsigned short)((u + 0x7FFFu + ((u >> 16) & 1u)) >> 16);
}
__device__ __forceinline__ unsigned int bfpk(float a, float b) {
  return (unsigned int)bf16c(a) | ((unsigned int)bf16c(b) << 16);
}

// ---------------------------------------------------------------------------
// prep: unchanged (round-8/13 exact).
// ---------------------------------------------------------------------------
__global__ void prep_kernel(const float* __restrict__ w_ih_d, const float* __restrict__ w_hh_d,
                            const float* __restrict__ b_ih_d, const float* __restrict__ b_hh_d,
                            const float* __restrict__ b_ih0, const float* __restrict__ b_hh0,
                            const float* __restrict__ b_ih1, const float* __restrict__ b_hh1,
                            const float* __restrict__ b_ih2, const float* __restrict__ b_hh2,
                            const float* __restrict__ w_hh0, const float* __restrict__ w_hh1,
                            const float* __restrict__ w_hh2,
                            const float* __restrict__ w_ih0, const float* __restrict__ w_ih1,
                            const float* __restrict__ w_ih2,
                            const float* __restrict__ fc_w0, const float* __restrict__ fc_w1,
                            const float* __restrict__ fc_w2,
                            unsigned short* __restrict__ dfeat_h,
                            float* __restrict__ biasd, float* __restrict__ bias0,
                            float* __restrict__ bias1, float* __restrict__ bias2,
                            unsigned int* __restrict__ wpk, unsigned int* __restrict__ wldsg,
                            unsigned int* __restrict__ wpk0, unsigned int* __restrict__ wpk1,
                            unsigned int* __restrict__ wpk2,
                            unsigned short* __restrict__ w0b, unsigned short* __restrict__ w1b,
                            unsigned short* __restrict__ w2b, unsigned short* __restrict__ wdb,
                            unsigned short* __restrict__ fcw0b, unsigned short* __restrict__ fcw1b,
                            unsigned short* __restrict__ fcw2b) {
  int idx = blockIdx.x * blockDim.x + threadIdx.x;
  int stride = gridDim.x * blockDim.x;
  for (int i = idx; i < 512 * 320; i += stride) {
    int r = i / 320, k = i % 320;
    w0b[i] = (k < 300) ? bf16c(w_ih0[(size_t)r * 300 + k]) : (unsigned short)0;
  }
  for (int i = idx; i < 256 * 128; i += stride) {
    int r = i >> 7, k = i & 127;
    w1b[i] = (k < 100) ? bf16c(w_ih1[(size_t)r * 100 + k]) : (unsigned short)0;
  }
  for (int i = idx; i < 512 * 512; i += stride) w2b[i] = bf16c(w_ih2[i]);
  for (int i = idx; i < 1024 * 256; i += stride) {
    int r = i >> 8, k = i & 255;
    wdb[i] = (k < 250) ? bf16c(w_ih_d[(size_t)r * 250 + k]) : (unsigned short)0;
  }
  for (int i = idx; i < 128 * 128; i += stride) {
    int f = i >> 7, k = i & 127;
    fcw0b[i] = (f < 100) ? bf16c(fc_w0[(size_t)f * 128 + k]) : (unsigned short)0;
    fcw2b[i] = (f < 100) ? bf16c(fc_w2[(size_t)f * 128 + k]) : (unsigned short)0;
  }
  for (int i = idx; i < 64 * 64; i += stride) {
    int f = i >> 6, k = i & 63;
    fcw1b[i] = (f < 50) ? bf16c(fc_w1[(size_t)f * 64 + k]) : (unsigned short)0;
  }
  for (int i = idx; i < M_ * 6; i += stride)   // zero dfeat_h pad cols 250..255
    dfeat_h[(size_t)(i / 6) * 256 + 250 + (i % 6)] = 0;
  for (int i = idx; i < 1024 * 96; i += stride) {
    int r = i / 96, k0 = (i % 96) * 2;
    wpk[i] = pk16(w_hh_d[(size_t)r * 256 + k0], w_hh_d[(size_t)r * 256 + k0 + 1]);
  }
  for (int i = idx; i < 32768; i += stride) {
    int jj = i >> 12, rem = i & 4095, r = rem >> 2, q = rem & 3;
    int p = 96 + 4 * jj + q;
    wldsg[i] = pk16(w_hh_d[(size_t)r * 256 + 2 * p], w_hh_d[(size_t)r * 256 + 2 * p + 1]);
  }
  for (int i = idx; i < 512 * 64; i += stride) {
    int r = i >> 6, p = (i & 63) * 2;
    wpk0[i] = pk16(w_hh0[(size_t)r * 128 + p], w_hh0[(size_t)r * 128 + p + 1]);
    wpk2[i] = pk16(w_hh2[(size_t)r * 128 + p], w_hh2[(size_t)r * 128 + p + 1]);
  }
  for (int i = idx; i < 256 * 32; i += stride) {
    int r = i >> 5, p = (i & 31) * 2;
    wpk1[i] = pk16(w_hh1[(size_t)r * 64 + p], w_hh1[(size_t)r * 64 + p + 1]);
  }
  for (int i = idx; i < 1024; i += stride) biasd[i] = b_ih_d[i] + b_hh_d[i];
  for (int i = idx; i < 512; i += stride) bias0[i] = b_ih0[i] + b_hh0[i];
  for (int i = idx; i < 256; i += stride) bias1[i] = b_ih1[i] + b_hh1[i];
  for (int i = idx; i < 512; i += stride) bias2[i] = b_ih2[i] + b_hh2[i];
}

// ---------------------------------------------------------------------------
// gemm128_body: 128x128 bf16 MFMA tile, 256 thr / 4 waves. Wave = 32x128
// slab: 2 A-frags x 8 B-frags = 16 MFMA per K-step(32) vs 10 ds_read_b128 —
// MFMA:DS cycle ratio ~3x better than the 64^2 tile (round-13 budget: the
// GEMM pair was the largest fixable term, DS-bound at 64^2).
// acc = 2x8 f32x4 = 64 VGPR (fits the 128-reg budget, no allocator fight).
// Same verified fragment layout / epilogue map as the 64^2 kernel.
// ---------------------------------------------------------------------------
template <bool XF16>
__device__ __forceinline__ void gemm128_body(
    const void* __restrict__ Xv, const unsigned short* __restrict__ Wb,
    const float* __restrict__ bias, const float* __restrict__ umask,
    float* __restrict__ C, int K, int Kp, int N, int d,
    unsigned short (*Xs)[40], unsigned short (*Ws)[40]) {
  const int tid = threadIdx.x;
  const int nx7 = (N >> 7) << 3;                 // n-tiles * 8
  const int n0 = ((d % nx7) >> 3) << 7;
  const int m0 = (((d / nx7) << 3) + (d & 7)) << 7;
  const int srow = tid >> 1, kq = tid & 1;       // staging: row, k-half(16 halves)
  const int w = tid >> 6, lane = tid & 63;
  const int lr = lane & 15, lk = lane >> 4;
  const int t = m0 >> 8, b0 = m0 & 255;          // m0 multiple of 128
  const float* Xf = nullptr;
  const unsigned short* Xh = nullptr;
  if constexpr (XF16) {
    Xh = (const unsigned short*)Xv + (size_t)(m0 + srow) * Kp;
  } else {
    Xf = (const float*)Xv + ((size_t)(b0 + srow) * T_ + t) * K;
  }
  const unsigned short* Wr = Wb + (size_t)(n0 + srow) * Kp;
  f32x4 acc[2][8];
#pragma unroll
  for (int a = 0; a < 2; a++)
#pragma unroll
    for (int j = 0; j < 8; j++) acc[a][j] = (f32x4){0.f, 0.f, 0.f, 0.f};

  for (int k0 = 0; k0 < Kp; k0 += 32) {
    const int kk = k0 + kq * 16;                 // 16 halves = 2 uint4
    uint4 xa0, xa1;
    if constexpr (XF16) {
      xa0 = *reinterpret_cast<const uint4*>(Xh + kk);
      xa1 = *reinterpret_cast<const uint4*>(Xh + kk + 8);
    } else {
      float4 v0 = (kk + 3  < K) ? *reinterpret_cast<const float4*>(Xf + kk)      : make_float4(0.f,0.f,0.f,0.f);
      float4 v1 = (kk + 7  < K) ? *reinterpret_cast<const float4*>(Xf + kk + 4)  : make_float4(0.f,0.f,0.f,0.f);
      float4 v2 = (kk + 11 < K) ? *reinterpret_cast<const float4*>(Xf + kk + 8)  : make_float4(0.f,0.f,0.f,0.f);
      float4 v3 = (kk + 15 < K) ? *reinterpret_cast<const float4*>(Xf + kk + 12) : make_float4(0.f,0.f,0.f,0.f);
      xa0.x = bfpk(v0.x, v0.y); xa0.y = bfpk(v0.z, v0.w);
      xa0.z = bfpk(v1.x, v1.y); xa0.w = bfpk(v1.z, v1.w);
      xa1.x = bfpk(v2.x, v2.y); xa1.y = bfpk(v2.z, v2.w);
      xa1.z = bfpk(v3.x, v3.y); xa1.w = bfpk(v3.z, v3.w);
    }
    uint4 wv0 = *reinterpret_cast<const uint4*>(Wr + kk);
    uint4 wv1 = *reinterpret_cast<const uint4*>(Wr + kk + 8);
    __syncthreads();   // previous tile's MFMA reads done
    *reinterpret_cast<uint4*>(&Xs[srow][kq * 16])     = xa0;
    *reinterpret_cast<uint4*>(&Xs[srow][kq * 16 + 8]) = xa1;
    *reinterpret_cast<uint4*>(&Ws[srow][kq * 16])     = wv0;
    *reinterpret_cast<uint4*>(&Ws[srow][kq * 16 + 8]) = wv1;
    __syncthreads();   // tiles staged
    short8 af0 = *reinterpret_cast<const short8*>(&Xs[w * 32 + lr][lk * 8]);
    short8 af1 = *reinterpret_cast<const short8*>(&Xs[w * 32 + 16 + lr][lk * 8]);
#pragma unroll
    for (int j = 0; j < 8; j++) {
      short8 bf = *reinterpret_cast<const short8*>(&Ws[j * 16 + lr][lk * 8]);
      acc[0][j] = __builtin_amdgcn_mfma_f32_16x16x32_bf16(af0, bf, acc[0][j], 0, 0, 0);
      acc[1][j] = __builtin_amdgcn_mfma_f32_16x16x32_bf16(af1, bf, acc[1][j], 0, 0, 0);
    }
  }
#pragma unroll
  for (int a = 0; a < 2; a++) {
#pragma unroll
    for (int j = 0; j < 8; j++) {
      const int col = n0 + j * 16 + lr;
      const float bv = bias[col];
#pragma unroll
      for (int r = 0; r < 4; r++) {
        const int roff = w * 32 + a * 16 + lk * 4 + r;
        const int mrow = m0 + roff;
        float um = 1.0f;
        if constexpr (!XF16) um = umask[(b0 + roff) * T_ + t];
        C[(size_t)mrow * N + col] = acc[a][j][r] * um + bv;
      }
    }
  }
}

// ---------------------------------------------------------------------------
// proj_all: 3 input-projection GEMMs, one launch, 128x128 tiles.
// Grid: [0,1024) mod0 | [1024,1536) mod1 | [1536,2560) mod2.
// ---------------------------------------------------------------------------
struct ProjArgs {
  const float* x0; const float* x1; const float* x2;
  const unsigned short* w0; const unsigned short* w1; const unsigned short* w2;
  const float* b0; const float* b1; const float* b2;
  float* c0; float* c1; float* c2;
};

__global__ __launch_bounds__(256) void proj_all(ProjArgs pa,
    const float* __restrict__ umask) {
  __shared__ __align__(16) unsigned short Xs[128][40];
  __shared__ __align__(16) unsigned short Ws[128][40];
  const int dg = blockIdx.x;
  if (dg < 1024)
    gemm128_body<false>(pa.x0, pa.w0, pa.b0, umask, pa.c0, 300, 320, 512, dg, Xs, Ws);
  else if (dg < 1536)
    gemm128_body<false>(pa.x1, pa.w1, pa.b1, umask, pa.c1, 100, 128, 256, dg - 1024, Xs, Ws);
  else
    gemm128_body<false>(pa.x2, pa.w2, pa.b2, umask, pa.c2, 512, 512, 512, dg - 1536, Xs, Ws);
}

// ---------------------------------------------------------------------------
// gxd_gemm: dialogue input projection (X bf16), 128x128 tiles, 2048 blocks.
// ---------------------------------------------------------------------------
__global__ __launch_bounds__(256) void gxd_gemm(
    const unsigned short* __restrict__ Xh, const unsigned short* __restrict__ Wb,
    const float* __restrict__ bias, float* __restrict__ C) {
  __shared__ __align__(16) unsigned short Xs[128][40];
  __shared__ __align__(16) unsigned short Ws[128][40];
  gemm128_body<true>(Xh, Wb, bias, nullptr, C, 256, 256, 1024, blockIdx.x, Xs, Ws);
}

// ---------------------------------------------------------------------------
// fc_all: 3 per-modality FC-head GEMMs, one launch (64^2 tiles — F small).
// ---------------------------------------------------------------------------
struct FcArgs {
  const unsigned short* x0; const unsigned short* x1; const unsigned short* x2;
  const unsigned short* w0; const unsigned short* w1; const unsigned short* w2;
  const float* b0; const float* b1; const float* b2;
};

__global__ __launch_bounds__(256) void fc_all(FcArgs fa,
    const float* __restrict__ umask, unsigned short* __restrict__ dfeat_h) {
  __shared__ __align__(16) unsigned short Xs[64][40];
  __shared__ __align__(16) unsigned short Ws[64][40];
  const int tid = threadIdx.x;
  const int dg = blockIdx.x;
  const unsigned short* Xh; const unsigned short* Wb; const float* fcb;
  int Kp, nx, F, col0, d;
  if (dg < 1024)      { Xh = fa.x0; Wb = fa.w0; fcb = fa.b0; Kp = 128; nx = 2; F = 100; col0 = 0;   d = dg; }
  else if (dg < 1536) { Xh = fa.x1; Wb = fa.w1; fcb = fa.b1; Kp = 64;  nx = 1; F = 50;  col0 = 100; d = dg - 1024; }
  else                { Xh = fa.x2; Wb = fa.w2; fcb = fa.b2; Kp = 128; nx = 2; F = 100; col0 = 150; d = dg - 1536; }
  const int n0 = (d % nx) * 64;
  const int m0 = (d / nx) * 64;
  const int srow = tid >> 2, kq = tid & 3;
  const int w = tid >> 6, lane = tid & 63;
  const int lr = lane & 15, lk = lane >> 4;
  const unsigned short* Xp = Xh + (size_t)(m0 + srow) * Kp;
  const unsigned short* Wr = Wb + (size_t)(n0 + srow) * Kp;
  f32x4 acc[4];
#pragma unroll
  for (int j = 0; j < 4; j++) acc[j] = (f32x4){0.f, 0.f, 0.f, 0.f};
  for (int k0 = 0; k0 < Kp; k0 += 32) {
    const int kk = k0 + kq * 8;
    uint4 xa = *reinterpret_cast<const uint4*>(Xp + kk);
    uint4 wv = *reinterpret_cast<const uint4*>(Wr + kk);
    __syncthreads();
    *reinterpret_cast<uint4*>(&Xs[srow][kq * 8]) = xa;
    *reinterpret_cast<uint4*>(&Ws[srow][kq * 8]) = wv;
    __syncthreads();
    short8 af = *reinterpret_cast<const short8*>(&Xs[w * 16 + lr][lk * 8]);
#pragma unroll
    for (int j = 0; j < 4; j++) {
      short8 bf = *reinterpret_cast<const short8*>(&Ws[j * 16 + lr][lk * 8]);
      acc[j] = __builtin_amdgcn_mfma_f32_16x16x32_bf16(af, bf, acc[j], 0, 0, 0);
    }
  }
#pragma unroll
  for (int j = 0; j < 4; j++) {
    const int coln = n0 + j * 16 + lr;
    const float bv = (coln < F) ? fcb[coln] : 0.f;
#pragma unroll
    for (int r = 0; r < 4; r++) {
      const int mrow = m0 + w * 16 + lk * 4 + r;
      if (coln < F) {
        const int t = mrow >> 8, b = mrow & 255;
        float um = umask[b * T_ + t];
        dfeat_h[(size_t)mrow * 256 + col0 + coln] = bf16c(tanhf(acc[j][r] + bv) * um);
      }
    }
  }
}

// ---------------------------------------------------------------------------
// mod_scan: round-8 exact (measured good): waves_per_eu(2,3), no pins.
// ---------------------------------------------------------------------------
struct ModScanArgs {
  const float* gx0; const float* gx1; const float* gx2;
  const unsigned int* wk0; const unsigned int* wk1; const unsigned int* wk2;
  unsigned short* hm0; unsigned short* hm1; unsigned short* hm2;
};

__device__ __forceinline__ void mod_body128s(
    const float* __restrict__ gx, const unsigned int* __restrict__ wk,
    int b, unsigned short* __restrict__ hallm, unsigned int* smem) {
  float* gbuf = (float*)smem;          // 512 f32
  unsigned int* hbuf = smem + 512;     // 64 u32
  const int tid = threadIdx.x;
  uint4 wrA[16], wrB[16];
  {
    const uint4* wpA = reinterpret_cast<const uint4*>(wk + (size_t)tid * 64);
    const uint4* wpB = reinterpret_cast<const uint4*>(wk + (size_t)(tid + 256) * 64);
#pragma unroll
    for (int j = 0; j < 16; j++) { wrA[j] = wpA[j]; wrB[j] = wpB[j]; }
  }
  if (tid < 64) hbuf[tid] = 0u;
  float creg = 0.f;
  __syncthreads();
  const uint4* h4 = reinterpret_cast<const uint4*>(hbuf);
  const float* gp = gx + (size_t)b * 512 + tid;
  float gcA = gp[0], gcB = gp[256];
  for (int t = 0; t < T_; t++) {
    float gnA = 0.f, gnB = 0.f;
    if (t + 1 < T_) {
      gnA = gp[(size_t)(t + 1) * B_ * 512];
      gnB = gp[(size_t)(t + 1) * B_ * 512 + 256];
    }
    float a0 = 0.f, a1 = 0.f, a2 = 0.f, a3 = 0.f;
    float d0 = 0.f, d1 = 0.f, d2 = 0.f, d3 = 0.f;
#pragma unroll
    for (int j = 0; j < 16; j++) {
      uint4 hv = h4[j];
      a0 = fdot2f(wrA[j].x, hv.x, a0);
      a1 = fdot2f(wrA[j].y, hv.y, a1);
      a2 = fdot2f(wrA[j].z, hv.z, a2);
      a3 = fdot2f(wrA[j].w, hv.w, a3);
      d0 = fdot2f(wrB[j].x, hv.x, d0);
      d1 = fdot2f(wrB[j].y, hv.y, d1);
      d2 = fdot2f(wrB[j].z, hv.z, d2);
      d3 = fdot2f(wrB[j].w, hv.w, d3);
    }
    gbuf[tid] = (a0 + a1) + (a2 + a3) + gcA;      // gx includes bias + umask'd x
    gbuf[tid + 256] = (d0 + d1) + (d2 + d3) + gcB;
    gcA = gnA; gcB = gnB;
    __syncthreads();                               // S1: gates ready
    if (tid < 128) {
      float i_ = sigf(gbuf[tid]);
      float f_ = sigf(gbuf[128 + tid]);
      float g_ = tanhf(gbuf[256 + tid]);
      float o_ = sigf(gbuf[384 + tid]);
      float cc = f_ * creg + i_ * g_;
      creg = cc;
      float h2 = tanhf(o_ * tanhf(cc));            // extra tanh on hidden state
      hallm[((size_t)t * B_ + b) * 128 + tid] = bf16c(h2);
      float hp = __shfl_xor(h2, 1);
      if ((tid & 1) == 0) hbuf[tid >> 1] = pk16(h2, hp);
    }
    __syncthreads();                               // S2: h_t staged
  }
}

__device__ __forceinline__ void mod_body64s(
    const float* __restrict__ gx, const unsigned int* __restrict__ wk,
    int b, unsigned short* __restrict__ hallm, unsigned int* smem) {
  float* gbuf = (float*)smem;          // 256 f32
  unsigned int* hbuf = smem + 512;     // 32 u32
  const int tid = threadIdx.x;
  uint4 wr[8];
  {
    const uint4* wp = reinterpret_cast<const uint4*>(wk + (size_t)tid * 32);
#pragma unroll
    for (int j = 0; j < 8; j++) wr[j] = wp[j];
  }
  if (tid < 32) hbuf[tid] = 0u;
  float creg = 0.f;
  __syncthreads();
  const uint4* h4 = reinterpret_cast<const uint4*>(hbuf);
  const float* gp = gx + (size_t)b * 256 + tid;
  float gc = gp[0];
  for (int t = 0; t < T_; t++) {
    float gn = (t + 1 < T_) ? gp[(size_t)(t + 1) * B_ * 256] : 0.f;
    float a0 = 0.f, a1 = 0.f, a2 = 0.f, a3 = 0.f;
#pragma unroll
    for (int j = 0; j < 8; j++) {
      uint4 hv = h4[j];
      a0 = fdot2f(wr[j].x, hv.x, a0);
      a1 = fdot2f(wr[j].y, hv.y, a1);
      a2 = fdot2f(wr[j].z, hv.z, a2);
      a3 = fdot2f(wr[j].w, hv.w, a3);
    }
    gbuf[tid] = (a0 + a1) + (a2 + a3) + gc;
    gc = gn;
    __syncthreads();                               // S1
    if (tid < 64) {
      float i_ = sigf(gbuf[tid]);
      float f_ = sigf(gbuf[64 + tid]);
      float g_ = tanhf(gbuf[128 + tid]);
      float o_ = sigf(gbuf[192 + tid]);
      float cc = f_ * creg + i_ * g_;
      creg = cc;
      float h2 = tanhf(o_ * tanhf(cc));
      hallm[((size_t)t * B_ + b) * 64 + tid] = bf16c(h2);
      float hp = __shfl_xor(h2, 1);
      if ((tid & 1) == 0) hbuf[tid >> 1] = pk16(h2, hp);
    }
    __syncthreads();                               // S2
  }
}

__global__ __launch_bounds__(256)
__attribute__((amdgpu_waves_per_eu(2, 3)))
void mod_scan(ModScanArgs a, unsigned short* __restrict__ hm_unused) {
  __shared__ __align__(16) unsigned int smem[576];   // gbuf(512) | hbuf(64)
  const int blk = blockIdx.x;
  if (blk < 512) {
    const int mi = blk >> 8, b = blk & 255;
    mod_body128s(mi ? a.gx2 : a.gx0, mi ? a.wk2 : a.wk0, b,
                 mi ? a.hm2 : a.hm0, smem);
  } else {
    mod_body64s(a.gx1, a.wk1, blk - 512, a.hm1, smem);
  }
}

// ---------------------------------------------------------------------------
// dlg_recur: round-8 exact (best measured: 283 µs; DS-pipe floor ~245).
// ---------------------------------------------------------------------------
#define DLG_LDS_BYTES (131072 + 4096 + 512)

__global__ __launch_bounds__(512, 2) void dlg_recur(
    const float* __restrict__ gxd, const unsigned int* __restrict__ wpk,
    const unsigned int* __restrict__ wldsg, float* __restrict__ hall) {
  extern __shared__ char smem[];
  unsigned int* wl = (unsigned int*)smem;                       // [8][1024][4]
  float* gbuf = (float*)(smem + 131072);                        // [1024]
  _Float16* hbuf_h = (_Float16*)(smem + 131072 + 4096);         // [256]
  const uint4* hbuf4 = (const uint4*)hbuf_h;                    // [32]
  const uint4* wl4 = (const uint4*)wl;
  const int tid = threadIdx.x;
  const int b = blockIdx.x;

  for (int i = tid; i < 32768; i += 512) wl[i] = wldsg[i];
  unsigned int wr0[96], wr1[96];
  {
    const uint4* p0 = reinterpret_cast<const uint4*>(wpk + (size_t)tid * 96);
    const uint4* p1 = reinterpret_cast<const uint4*>(wpk + (size_t)(tid + 512) * 96);
#pragma unroll
    for (int j = 0; j < 24; j++) {
      uint4 v0 = p0[j], v1 = p1[j];
      wr0[4 * j + 0] = v0.x; wr0[4 * j + 1] = v0.y; wr0[4 * j + 2] = v0.z; wr0[4 * j + 3] = v0.w;
      wr1[4 * j + 0] = v1.x; wr1[4 * j + 1] = v1.y; wr1[4 * j + 2] = v1.z; wr1[4 * j + 3] = v1.w;
    }
  }
  if (tid < 32) reinterpret_cast<uint4*>(const_cast<_Float16*>(hbuf_h))[tid] = uint4{0, 0, 0, 0};
  float creg = 0.f;
  __syncthreads();

  const float* gbase = gxd + (size_t)b * 1024 + tid;
  float gc0 = gbase[0], gc1 = gbase[512];
  for (int t = 0; t < T_; t++) {
    float gn0 = 0.f, gn1 = 0.f;
    if (t + 1 < T_) {
      gn0 = gbase[(size_t)(t + 1) * B_ * 1024];
      gn1 = gbase[(size_t)(t + 1) * B_ * 1024 + 512];
    }
    float a0 = 0.f, a1 = 0.f;
#pragma unroll
    for (int j = 0; j < 24; j++) {          // pairs 0..95 (registers)
      uint4 hv = hbuf4[j];
      a0 = fdot2f(wr0[4 * j + 0], hv.x, a0); a1 = fdot2f(wr1[4 * j + 0], hv.x, a1);
      a0 = fdot2f(wr0[4 * j + 1], hv.y, a0); a1 = fdot2f(wr1[4 * j + 1], hv.y, a1);
      a0 = fdot2f(wr0[4 * j + 2], hv.z, a0); a1 = fdot2f(wr1[4 * j + 2], hv.z, a1);
      a0 = fdot2f(wr0[4 * j + 3], hv.w, a0); a1 = fdot2f(wr1[4 * j + 3], hv.w, a1);
    }
#pragma unroll
    for (int jj = 0; jj < 8; jj++) {        // pairs 96..127 (LDS, b128)
      uint4 hv = hbuf4[24 + jj];
      uint4 wa = wl4[jj * 1024 + tid];
      uint4 wc = wl4[jj * 1024 + tid + 512];
      a0 = fdot2f(wa.x, hv.x, a0); a1 = fdot2f(wc.x, hv.x, a1);
      a0 = fdot2f(wa.y, hv.y, a0); a1 = fdot2f(wc.y, hv.y, a1);
      a0 = fdot2f(wa.z, hv.z, a0); a1 = fdot2f(wc.z, hv.z, a1);
      a0 = fdot2f(wa.w, hv.w, a0); a1 = fdot2f(wc.w, hv.w, a1);
    }
    gbuf[tid] = a0 + gc0;
    gbuf[tid + 512] = a1 + gc1;
    __syncthreads();
    if (tid < DH_) {
      float i_ = sigf(gbuf[tid]);
      float f_ = sigf(gbuf[DH_ + tid]);
      float g_ = tanhf(gbuf[2 * DH_ + tid]);
      float o_ = sigf(gbuf[3 * DH_ + tid]);
      float c2 = f_ * creg + i_ * g_;
      creg = c2;
      float h2 = o_ * tanhf(c2);
      hall[((size_t)t * B_ + b) * DH_ + tid] = h2;
      hbuf_h[tid] = (_Float16)h2;
    }
    gc0 = gn0; gc1 = gn1;
    __syncthreads();
  }
}

// ---------------------------------------------------------------------------
// out_head: fc_out + tanh + smax + log_softmax (unchanged).
// ---------------------------------------------------------------------------
__global__ __launch_bounds__(256) void out_head(
    const float* __restrict__ hall, const float* __restrict__ fcow,
    const float* __restrict__ fcob, const float* __restrict__ smw,
    const float* __restrict__ smb, float* __restrict__ out) {
  __shared__ __align__(16) float h_lds[16][260];
  __shared__ __align__(16) float fco[16][132];
  __shared__ float lg[16][6];
  const int tid = threadIdx.x;
  const int m0 = blockIdx.x * 16;
  {
    const float* src = hall + (size_t)m0 * DH_;
    for (int e = tid; e < 1024; e += 256) {
      float4 v = reinterpret_cast<const float4*>(src)[e];
      const int r = e >> 6, k = (e & 63) * 4;
      *reinterpret_cast<float4*>(&h_lds[r][k]) = v;
    }
  }
  __syncthreads();
  {
    const int f = tid & 127, half = tid >> 7;
    float acc[8];
    const float fb = fcob[f];
#pragma unroll
    for (int r = 0; r < 8; r++) acc[r] = fb;
    const float* wrow = fcow + (size_t)f * DH_;
    for (int k = 0; k < DH_; k += 4) {
      float4 w4 = *reinterpret_cast<const float4*>(wrow + k);
#pragma unroll
      for (int r = 0; r < 8; r++)
        acc[r] += dot4(w4, *reinterpret_cast<const float4*>(&h_lds[half * 8 + r][k]));
    }
#pragma unroll
    for (int r = 0; r < 8; r++) fco[half * 8 + r][f] = tanhf(acc[r]);
  }
  __syncthreads();
  if (tid < 96) {
    const int r = tid / 6, cc = tid % 6;
    float a = smb[cc];
    const float* sw = smw + cc * 128;
#pragma unroll 4
    for (int k = 0; k < 128; k++) a += sw[k] * fco[r][k];
    lg[r][cc] = a;
  }
  __syncthreads();
  if (tid < 16) {
    const int m = m0 + tid;
    const int t = m >> 8, b = m & 255;
    float mx = lg[tid][0];
#pragma unroll
    for (int cc = 1; cc < 6; cc++) mx = fmaxf(mx, lg[tid][cc]);
    float ssum = 0.f;
#pragma unroll
    for (int cc = 0; cc < 6; cc++) ssum += __expf(lg[tid][cc] - mx);
    float lse = mx + logf(ssum);
#pragma unroll
    for (int cc = 0; cc < 6; cc++)
      out[((size_t)b * T_ + t) * 6 + cc] = lg[tid][cc] - lse;
  }
}

// ---------------------------------------------------------------------------
extern "C" void kernel_launch(void* const* d_in, const int* in_sizes, int n_in,
                              void* d_out, int out_size, void* d_ws, size_t ws_size,
                              hipStream_t stream) {
  const float* mod0  = (const float*)d_in[0];
  const float* mod1  = (const float*)d_in[1];
  const float* mod2  = (const float*)d_in[2];
  const float* umask = (const float*)d_in[3];
  const float* w_ih0 = (const float*)d_in[4];
  const float* w_hh0 = (const float*)d_in[5];
  const float* b_ih0 = (const float*)d_in[6];
  const float* b_hh0 = (const float*)d_in[7];
  const float* fc_w0 = (const float*)d_in[8];
  const float* fc_b0 = (const float*)d_in[9];
  const float* w_ih1 = (const float*)d_in[10];
  const float* w_hh1 = (const float*)d_in[11];
  const float* b_ih1 = (const float*)d_in[12];
  const float* b_hh1 = (const float*)d_in[13];
  const float* fc_w1 = (const float*)d_in[14];
  const float* fc_b1 = (const float*)d_in[15];
  const float* w_ih2 = (const float*)d_in[16];
  const float* w_hh2 = (const float*)d_in[17];
  const float* b_ih2 = (const float*)d_in[18];
  const float* b_hh2 = (const float*)d_in[19];
  const float* fc_w2 = (const float*)d_in[20];
  const float* fc_b2 = (const float*)d_in[21];
  const float* w_ih_d = (const float*)d_in[22];
  const float* w_hh_d = (const float*)d_in[23];
  const float* b_ih_d = (const float*)d_in[24];
  const float* b_hh_d = (const float*)d_in[25];
  const float* fco_w  = (const float*)d_in[26];
  const float* fco_b  = (const float*)d_in[27];
  const float* sm_w   = (const float*)d_in[28];
  const float* sm_b   = (const float*)d_in[29];

  // workspace layout (float units):
  //   [0, M*1280): gx0|gx1|gx2 -> reused as gxd [0,M*1024)
  //   [M*1024, M*1280): hallm0|hallm2|hallm1 (bf16) -> later hall (fp32)
  float* ws    = (float*)d_ws;
  float* gx0   = ws;                                  // M*512
  float* gx1   = gx0 + (size_t)M_ * 512;              // M*256
  float* gx2   = gx1 + (size_t)M_ * 256;              // M*512
  float* gxd   = ws;                                  // M*1024 (reuse)
  float* hall  = ws + (size_t)M_ * 1024;              // M*256 fp32
  unsigned short* hm0 = (unsigned short*)(ws + (size_t)M_ * 1024);  // M*128 bf16
  unsigned short* hm2 = hm0 + (size_t)M_ * 128;                     // M*128 bf16
  unsigned short* hm1 = hm2 + (size_t)M_ * 128;                     // M*64 bf16
  unsigned short* dfeat_h = (unsigned short*)(ws + (size_t)M_ * 1280);  // M*256 bf16
  float* tail  = ws + (size_t)M_ * 1408;
  float* biasd = tail;                                // 1024
  float* bias0 = biasd + 1024;                        // 512
  float* bias1 = bias0 + 512;                         // 256
  float* bias2 = bias1 + 256;                         // 512
  unsigned int* wpk   = (unsigned int*)(bias2 + 512); // 1024*96
  unsigned int* wldsg = wpk + 1024 * 96;              // 32768
  unsigned int* wpk0  = wldsg + 32768;                // 512*64
  unsigned int* wpk1  = wpk0 + 512 * 64;              // 256*32
  unsigned int* wpk2  = wpk1 + 256 * 32;              // 512*64
  unsigned short* w0b = (unsigned short*)(wpk2 + 512 * 64);  // 512*320
  unsigned short* w1b = w0b + 512 * 320;                     // 256*128
  unsigned short* w2b = w1b + 256 * 128;                     // 512*512
  unsigned short* wdb = w2b + 512 * 512;                     // 1024*256
  unsigned short* fcw0b = wdb + 1024 * 256;                  // 128*128
  unsigned short* fcw1b = fcw0b + 128 * 128;                 // 64*64
  unsigned short* fcw2b = fcw1b + 64 * 64;                   // 128*128

  prep_kernel<<<256, 256, 0, stream>>>(w_ih_d, w_hh_d, b_ih_d, b_hh_d,
      b_ih0, b_hh0, b_ih1, b_hh1, b_ih2, b_hh2,
      w_hh0, w_hh1, w_hh2, w_ih0, w_ih1, w_ih2, fc_w0, fc_w1, fc_w2,
      dfeat_h, biasd, bias0, bias1, bias2, wpk, wldsg,
      wpk0, wpk1, wpk2, w0b, w1b, w2b, wdb, fcw0b, fcw1b, fcw2b);

  // input projections (bf16 MFMA, 128x128 tiles, one launch)
  ProjArgs pa;
  pa.x0 = mod0; pa.x1 = mod1; pa.x2 = mod2;
  pa.w0 = w0b;  pa.w1 = w1b;  pa.w2 = w2b;
  pa.b0 = bias0; pa.b1 = bias1; pa.b2 = bias2;
  pa.c0 = gx0;  pa.c1 = gx1;  pa.c2 = gx2;
  proj_all<<<2560, 256, 0, stream>>>(pa, umask);

  // fused modality scans (FC evicted; h -> hallm bf16)
  ModScanArgs a;
  a.gx0 = gx0; a.gx1 = gx1; a.gx2 = gx2;
  a.wk0 = wpk0; a.wk1 = wpk1; a.wk2 = wpk2;
  a.hm0 = hm0; a.hm1 = hm1; a.hm2 = hm2;
  mod_scan<<<768, 256, 0, stream>>>(a, nullptr);

  // FC heads (bf16 MFMA) -> dfeat, one launch
  FcArgs fa;
  fa.x0 = hm0; fa.x1 = hm1; fa.x2 = hm2;
  fa.w0 = fcw0b; fa.w1 = fcw1b; fa.w2 = fcw2b;
  fa.b0 = fc_b0; fa.b1 = fc_b1; fa.b2 = fc_b2;
  fc_all<<<2560, 256, 0, stream>>>(fa, umask, dfeat_h);

  // dialogue input projection (bf16 MFMA, X bf16, 128x128 tiles)
  gxd_gemm<<<2048, 256, 0, stream>>>(dfeat_h, wdb, biasd, gxd);

  hipFuncSetAttribute(reinterpret_cast<const void*>(dlg_recur),
                      hipFuncAttributeMaxDynamicSharedMemorySize, DLG_LDS_BYTES);
  dlg_recur<<<256, 512, DLG_LDS_BYTES, stream>>>(gxd, wpk, wldsg, hall);

  out_head<<<M_ / 16, 256, 0, stream>>>(hall, fco_w, fco_b, sm_w, sm_b, (float*)d_out);
}